// Round 12
// baseline (715.281 us; speedup 1.0000x reference)
//
#include <hip/hip_runtime.h>

// ---------- constants ----------
#define DMODEL   1024
#define DINNER   2048
#define NHEADS   32
#define DHEAD    64
#define DSTATE   64
#define CONVDIM  2176
#define DINPROJ  4256
#define LSEQ     4096
#define BSZ      2
#define NCHUNK   16
#define CHUNK    256
#define NROWS    8192      // BSZ*LSEQ
#define NPAD     4352      // 17*256, padded in_proj rows
#define XT_P     264       // LDS transpose pitch (mult of 8, 2-way banks)
#define M_P      40        // M tile pitch

typedef __attribute__((ext_vector_type(8))) short  short8;
typedef __attribute__((ext_vector_type(4))) float  f32x4;
typedef __attribute__((ext_vector_type(4))) unsigned short us4;

__device__ __forceinline__ float bf2f(unsigned short u){
  return __uint_as_float(((unsigned int)u) << 16);
}
__device__ __forceinline__ unsigned short f2bf(float f){
  unsigned int i = __float_as_uint(f);
  i += 0x7fffu + ((i >> 16) & 1u);     // round-to-nearest-even
  return (unsigned short)(i >> 16);
}

// async global->LDS, 16B per lane (dest = wave-uniform base + lane*16)
__device__ __forceinline__ void gl_lds16(const void* g, void* l){
  __builtin_amdgcn_global_load_lds(
      (const __attribute__((address_space(1))) unsigned int*)g,
      (__attribute__((address_space(3))) unsigned int*)l, 16, 0, 0);
}

// ---------- cast f32 weights -> bf16 (optionally zero-pad extra rows) ----------
__global__ void cast_pad_kernel(const float* __restrict__ src, unsigned short* __restrict__ dst,
                                int rows_src, int cols, long long total){
  long long i = (long long)blockIdx.x * 256 + threadIdx.x;
  if (i >= total) return;
  long long r = i / cols;
  dst[i] = (r < rows_src) ? f2bf(src[i]) : (unsigned short)0;
}

// ---------- RMSNorm (f32 in -> bf16 out), row = 1024 ----------
__global__ void rmsnorm_kernel(const float* __restrict__ x, const float* __restrict__ w,
                               unsigned short* __restrict__ out){
  int r = blockIdx.x, t = threadIdx.x;
  const float* xr = x + (size_t)r * DMODEL;
  float v[4]; float s = 0.f;
#pragma unroll
  for (int i = 0; i < 4; ++i){ v[i] = xr[t + i*256]; s += v[i]*v[i]; }
  __shared__ float red[4];
  for (int off = 32; off; off >>= 1) s += __shfl_down(s, off, 64);
  if ((t & 63) == 0) red[t >> 6] = s;
  __syncthreads();
  s = red[0] + red[1] + red[2] + red[3];
  float sc = rsqrtf(s * (1.f/DMODEL) + 1e-5f);
#pragma unroll
  for (int i = 0; i < 4; ++i)
    out[(size_t)r*DMODEL + t + i*256] = f2bf(v[i]*sc*w[t + i*256]);
}

// ---------- 256x256 counted-vmcnt bf16 MFMA GEMM (C = A.B^T), BK=64 ----------
// 8 waves (2M x 4N), per-wave 128x64 out. 2-slot LDS dbuf (128 KiB), T2 XOR
// swizzle (16B slot ^= row&7; both-sides: pre-swizzled global src keeps the
// gl_lds dest linear — rule 21). Per K-step: {stage t+1 (8 loads) -> vmcnt(8)
// counted -> bar1 -> 2x(12 swizzled ds_read + 32 MFMA) -> lgkmcnt(0) -> bar2}.
// Race-free: stage into slot (t+1)&1 happens only after bar2 of step t-1
// (whose readers drained via lgkmcnt(0)); vmcnt(8) leaves only t+1's loads live.
template<int EPI>
__launch_bounds__(512, 1)
__global__ void gemm256_bt(const unsigned short* __restrict__ A, const unsigned short* __restrict__ Bw,
                           void* __restrict__ Cout, const float* __restrict__ Cres,
                           int K, int Nstore, int nbx){
  __shared__ __align__(16) unsigned short As[2][256*64];
  __shared__ __align__(16) unsigned short Bs[2][256*64];
  const int id = blockIdx.x;
  const int m0 = (id / nbx) * 256, n0 = (id % nbx) * 256;
  const int t = threadIdx.x, w = t >> 6, lane = t & 63;
  const int wr = w >> 2, wc = w & 3;       // 2M x 4N waves
  const int nt = K >> 6;
  const int swz = ((lane & 7) ^ (lane >> 3)) * 8;   // pre-swizzled source col (elems)

  auto STAGE = [&](int slot, int tile){
    const int k0 = tile << 6;
#pragma unroll
    for (int i = 0; i < 4; ++i){
      int rA = i*64 + w*8 + (lane >> 3);   // row within 256-tile
      gl_lds16(A  + (size_t)(m0 + rA)*K + k0 + swz, &As[slot][i*4096 + w*512]);
      gl_lds16(Bw + (size_t)(n0 + rA)*K + k0 + swz, &Bs[slot][i*4096 + w*512]);
    }
  };

  f32x4 acc[8][4] = {};
  STAGE(0, 0);
  for (int tt = 0; tt < nt; ++tt){
    if (tt + 1 < nt){
      STAGE((tt+1)&1, tt+1);
      asm volatile("s_waitcnt vmcnt(8)" ::: "memory");   // tile tt resident; t+1 in flight
    } else {
      asm volatile("s_waitcnt vmcnt(0)" ::: "memory");
    }
    __builtin_amdgcn_s_barrier();          // bar1: tile tt resident for ALL waves
    const unsigned short* Ab = As[tt&1];
    const unsigned short* Bb = Bs[tt&1];
#pragma unroll
    for (int k2 = 0; k2 < 2; ++k2){
      short8 af[8], bv[4];
      const int slot = k2*4 + (lane >> 4);
#pragma unroll
      for (int mf = 0; mf < 8; ++mf){
        int row = wr*128 + mf*16 + (lane & 15);
        af[mf] = *(const short8*)&Ab[row*64 + ((slot ^ (row & 7)) * 8)];
      }
#pragma unroll
      for (int nf = 0; nf < 4; ++nf){
        int row = wc*64 + nf*16 + (lane & 15);
        bv[nf] = *(const short8*)&Bb[row*64 + ((slot ^ (row & 7)) * 8)];
      }
      __builtin_amdgcn_s_setprio(1);
#pragma unroll
      for (int mf = 0; mf < 8; ++mf)
#pragma unroll
        for (int nf = 0; nf < 4; ++nf)
          acc[mf][nf] = __builtin_amdgcn_mfma_f32_16x16x32_bf16(af[mf], bv[nf], acc[mf][nf], 0, 0, 0);
      __builtin_amdgcn_s_setprio(0);
    }
    asm volatile("s_waitcnt lgkmcnt(0)" ::: "memory");   // all reads of slot tt&1 done
    __builtin_amdgcn_s_barrier();          // bar2: collective read-done fence
  }

#pragma unroll
  for (int mf = 0; mf < 8; ++mf){
#pragma unroll
    for (int nf = 0; nf < 4; ++nf){
      int col = n0 + wc*64 + nf*16 + (lane & 15);
      if (col < Nstore){
#pragma unroll
        for (int r = 0; r < 4; ++r){
          int row = m0 + wr*128 + mf*16 + (lane >> 4)*4 + r;
          if (EPI == 0)
            ((unsigned short*)Cout)[(size_t)row*Nstore + col] = f2bf(acc[mf][nf][r]);
          else
            ((float*)Cout)[(size_t)row*Nstore + col] =
                Cres[(size_t)row*Nstore + col] + acc[mf][nf][r];
        }
      }
    }
  }
}

// ---------- bf16 MFMA GEMM, 128x128 (m97 structure) — out_proj ----------
template<int EPI>
__launch_bounds__(256, 3)
__global__ void gemm_bt(const unsigned short* __restrict__ A, const unsigned short* __restrict__ Bw,
                        void* __restrict__ Cout, const float* __restrict__ Cres,
                        int K, int Nstore, int nbx){
  __shared__ __align__(16) unsigned short As[128*64];
  __shared__ __align__(16) unsigned short Bs[128*64];
  const int id = blockIdx.x;
  const int m0 = (id / nbx) * 128, n0 = (id % nbx) * 128;
  const int t = threadIdx.x, w = t >> 6, lane = t & 63;
  const int wr = w >> 1, wc = w & 1;
  const int srow = lane >> 3;           // 0..7
  const int scol = (lane & 7) * 8;      // 0..56
  f32x4 acc[4][4] = {};

  for (int k0 = 0; k0 < K; k0 += 64){
#pragma unroll
    for (int it = 0; it < 4; ++it){
      int rr = (w*4 + it)*8 + srow;
      gl_lds16(A  + (size_t)(m0 + rr)*K + k0 + scol, &As[(w*4 + it)*512]);
      gl_lds16(Bw + (size_t)(n0 + rr)*K + k0 + scol, &Bs[(w*4 + it)*512]);
    }
    __syncthreads();
#pragma unroll
    for (int kk = 0; kk < 64; kk += 32){
      short8 af[4], bfr[4];
      int col = kk + (lane >> 4)*8;
#pragma unroll
      for (int m = 0; m < 4; ++m)
        af[m] = *(const short8*)&As[(wr*64 + m*16 + (lane & 15))*64 + col];
#pragma unroll
      for (int n = 0; n < 4; ++n)
        bfr[n] = *(const short8*)&Bs[(wc*64 + n*16 + (lane & 15))*64 + col];
#pragma unroll
      for (int m = 0; m < 4; ++m)
#pragma unroll
        for (int n = 0; n < 4; ++n)
          acc[m][n] = __builtin_amdgcn_mfma_f32_16x16x32_bf16(af[m], bfr[n], acc[m][n], 0, 0, 0);
    }
    __syncthreads();
  }

#pragma unroll
  for (int m = 0; m < 4; ++m){
#pragma unroll
    for (int n = 0; n < 4; ++n){
      int col = n0 + wc*64 + n*16 + (lane & 15);
      if (col < Nstore){
#pragma unroll
        for (int r = 0; r < 4; ++r){
          int row = m0 + wr*64 + m*16 + (lane >> 4)*4 + r;
          if (EPI == 0)
            ((unsigned short*)Cout)[(size_t)row*Nstore + col] = f2bf(acc[m][n][r]);
          else
            ((float*)Cout)[(size_t)row*Nstore + col] =
                Cres[(size_t)row*Nstore + col] + acc[m][n][r];
        }
      }
    }
  }
}

// ---------- causal conv1d (K=4) + silu, 8 channels/thread, rolling taps ----------
__global__ void conv_silu_kernel(const unsigned short* __restrict__ zx,
                                 const float* __restrict__ cw, const float* __restrict__ cb,
                                 unsigned short* __restrict__ X, unsigned short* __restrict__ Bm,
                                 unsigned short* __restrict__ Cm){
  int gid = blockIdx.x*256 + threadIdx.x;
  if (gid >= (CONVDIM/8)*(NROWS/64)) return;
  const int oc = gid % (CONVDIM/8);
  const int rb = gid / (CONVDIM/8);
  const int c = oc*8;
  const size_t r0 = (size_t)rb*64;
  const int l0 = (int)(r0 & (LSEQ-1));
  float w[4][8], bias[8];
#pragma unroll
  for (int j = 0; j < 8; ++j){
    bias[j] = cb[c+j];
#pragma unroll
    for (int i = 0; i < 4; ++i) w[i][j] = cw[(c+j)*4 + i];
  }
  const unsigned short* src = zx + DINNER + c;
  float p[3][8];
#pragma unroll
  for (int i = 0; i < 3; ++i){
    if (l0 - 3 + i >= 0){
      short8 v = *(const short8*)(src + (r0 - 3 + i)*DINPROJ);
#pragma unroll
      for (int j = 0; j < 8; ++j) p[i][j] = bf2f((unsigned short)v[j]);
    } else {
#pragma unroll
      for (int j = 0; j < 8; ++j) p[i][j] = 0.f;
    }
  }
  for (int it = 0; it < 64; ++it){
    const size_t r = r0 + it;
    short8 v = *(const short8*)(src + r*DINPROJ);
    float cur[8];
    short8 ov;
#pragma unroll
    for (int j = 0; j < 8; ++j){
      cur[j] = bf2f((unsigned short)v[j]);
      float a = bias[j] + w[0][j]*p[0][j] + w[1][j]*p[1][j] + w[2][j]*p[2][j] + w[3][j]*cur[j];
      float s = a / (1.f + __expf(-a));
      ov[j] = (short)f2bf(s);
    }
    if (c < DINNER)             *(short8*)(X  + r*DINNER + c) = ov;
    else if (c < DINNER+DSTATE) *(short8*)(Bm + r*DSTATE + (c-DINNER)) = ov;
    else                        *(short8*)(Cm + r*DSTATE + (c-DINNER-DSTATE)) = ov;
#pragma unroll
    for (int j = 0; j < 8; ++j){ p[0][j]=p[1][j]; p[1][j]=p[2][j]; p[2][j]=cur[j]; }
  }
}

// ---------- dt softplus + per-chunk inclusive cumsum of dA ----------
__global__ void dtscan_kernel(const unsigned short* __restrict__ zx, const float* __restrict__ dtb,
                              const float* __restrict__ A_log,
                              float* __restrict__ dt_sp, float* __restrict__ dAcs_g){
  const int z = blockIdx.x, hh = blockIdx.y, b = blockIdx.z;
  const int t = threadIdx.x;
  __shared__ float sdA[CHUNK];
  const float Ah = -__expf(A_log[hh]);
  size_t r = (size_t)b*LSEQ + z*CHUNK + t;
  float raw = bf2f(zx[r*DINPROJ + DINNER + CONVDIM + hh]) + dtb[hh];
  float dtv = raw > 20.f ? raw : log1pf(__expf(raw));
  sdA[t] = dtv * Ah;
  __syncthreads();
  for (int off = 1; off < CHUNK; off <<= 1){
    float v = (t >= off) ? sdA[t - off] : 0.f;
    __syncthreads();
    sdA[t] += v;
    __syncthreads();
  }
  size_t hb = (size_t)(b*NHEADS + hh);
  dt_sp[hb*LSEQ + z*CHUNK + t] = dtv;
  dAcs_g[(hb*NCHUNK + z)*CHUNK + t] = sdA[t];
}

// ---------- per-(b,chunk,head): states + within-chunk Yd, all MFMA ----------
__launch_bounds__(256, 2)
__global__ void chunk_main_kernel(const unsigned short* __restrict__ X,
                                  const unsigned short* __restrict__ Bm,
                                  const unsigned short* __restrict__ Cm,
                                  const float* __restrict__ dt_sp,
                                  const float* __restrict__ dAcs_g,
                                  float* __restrict__ states,
                                  unsigned short* __restrict__ Yb){
  const int z = blockIdx.x, hh = blockIdx.y, b = blockIdx.z;
  const int t = threadIdx.x, w = t >> 6, lane = t & 63;
  __shared__ __align__(16) unsigned short Xt[64 * XT_P];   // Xdt^T [p][l]
  __shared__ __align__(16) unsigned short U[64 * XT_P];    // union: Btdec -> M tiles -> Ystage
  __shared__ float sdA[CHUNK];
  __shared__ float sdt[CHUNK];

  const size_t row0 = (size_t)b*LSEQ + z*CHUNK;
  const size_t hb = (size_t)(b*NHEADS + hh);
  sdA[t] = dAcs_g[(hb*NCHUNK + z)*CHUNK + t];
  sdt[t] = dt_sp[hb*LSEQ + z*CHUNK + t];
  __syncthreads();
  const float total = sdA[CHUNK-1];

  // stage Xt[p][l] = X[l][p]*dt[l], U=Btdec[n][l] = B[l][n]*exp(total-sdA[l])
  for (int it = 0; it < 16; ++it){
    int l = it*16 + (t >> 4);
    int p4 = (t & 15) * 4;
    float dtl = sdt[l];
    float dec = __expf(total - sdA[l]);
    us4 xv = *(const us4*)(X  + (row0 + l)*DINNER + hh*DHEAD + p4);
    us4 bv = *(const us4*)(Bm + (row0 + l)*DSTATE + p4);
#pragma unroll
    for (int j = 0; j < 4; ++j){
      Xt[(p4 + j)*XT_P + l] = f2bf(bf2f(xv[j]) * dtl);
      U [(p4 + j)*XT_P + l] = f2bf(bf2f(bv[j]) * dec);
    }
  }
  __syncthreads();

  // ---- states: D[n][p] = sum_l Btdec[n][l] * Xt[p][l]; wave w owns n-tile w
  {
    f32x4 sacc[4] = {};
    for (int k2 = 0; k2 < 8; ++k2){
      int kc = k2*32 + (lane >> 4)*8;
      short8 a = *(const short8*)&U[(w*16 + (lane & 15))*XT_P + kc];
#pragma unroll
      for (int pt = 0; pt < 4; ++pt){
        short8 bfr = *(const short8*)&Xt[(pt*16 + (lane & 15))*XT_P + kc];
        sacc[pt] = __builtin_amdgcn_mfma_f32_16x16x32_bf16(a, bfr, sacc[pt], 0, 0, 0);
      }
    }
    float* sp = states + (((size_t)b*NCHUNK + z)*NHEADS + hh)*(DHEAD*DSTATE);
#pragma unroll
    for (int pt = 0; pt < 4; ++pt){
      int p = pt*16 + (lane & 15);
#pragma unroll
      for (int r = 0; r < 4; ++r){
        int n = w*16 + (lane >> 4)*4 + r;
        sp[p*DSTATE + n] = sacc[pt][r];
      }
    }
  }
  __syncthreads();   // Btdec dead; U becomes per-wave M tiles

  // ---- Yd: wave w owns l-tiles {w, w+4, w+8, w+12} (balanced triangle)
  unsigned short* Mw = U + w * (64 * M_P);
  short8 cfr[4][2];
#pragma unroll
  for (int lt = 0; lt < 4; ++lt){
    int lg = w + lt*4;
#pragma unroll
    for (int k2 = 0; k2 < 2; ++k2)
      cfr[lt][k2] = *(const short8*)(Cm + (row0 + lg*16 + (lane & 15))*DSTATE + k2*32 + (lane >> 4)*8);
  }
  f32x4 yacc[4][4] = {};
  for (int st = 0; st < 8; ++st){
    short8 gb[2][2];
#pragma unroll
    for (int ss = 0; ss < 2; ++ss)
#pragma unroll
      for (int k2 = 0; k2 < 2; ++k2)
        gb[ss][k2] = *(const short8*)(Bm + (row0 + st*32 + ss*16 + (lane & 15))*DSTATE + k2*32 + (lane >> 4)*8);
    short8 xb[4];
#pragma unroll
    for (int pt = 0; pt < 4; ++pt)
      xb[pt] = *(const short8*)&Xt[(pt*16 + (lane & 15))*XT_P + st*32 + (lane >> 4)*8];
#pragma unroll
    for (int lt = 0; lt < 4; ++lt){
      int lg = w + lt*4;
      if (st*32 > lg*16 + 15) continue;          // s-tile fully above diagonal
#pragma unroll
      for (int ss = 0; ss < 2; ++ss){
        f32x4 g = {};
        g = __builtin_amdgcn_mfma_f32_16x16x32_bf16(cfr[lt][0], gb[ss][0], g, 0, 0, 0);
        g = __builtin_amdgcn_mfma_f32_16x16x32_bf16(cfr[lt][1], gb[ss][1], g, 0, 0, 0);
        int s = st*32 + ss*16 + (lane & 15);
        float sdAs = sdA[s];
#pragma unroll
        for (int r = 0; r < 4; ++r){
          int l = lg*16 + (lane >> 4)*4 + r;
          float m = (s <= l) ? __expf(sdA[l] - sdAs) : 0.f;
          Mw[(lt*16 + (lane >> 4)*4 + r)*M_P + ss*16 + (lane & 15)] = f2bf(g[r] * m);
        }
      }
      short8 mf = *(const short8*)&Mw[(lt*16 + (lane & 15))*M_P + (lane >> 4)*8];
#pragma unroll
      for (int pt = 0; pt < 4; ++pt)
        yacc[lt][pt] = __builtin_amdgcn_mfma_f32_16x16x32_bf16(mf, xb[pt], yacc[lt][pt], 0, 0, 0);
    }
  }
  __syncthreads();   // M dead; U becomes Ystage

  // ---- stage Y (bf16, XOR-swizzled 8-elem blocks) and write out coalesced
  unsigned short* Yst = U + w * 4096;
#pragma unroll
  for (int lt = 0; lt < 4; ++lt)
#pragma unroll
    for (int pt = 0; pt < 4; ++pt)
#pragma unroll
      for (int r = 0; r < 4; ++r){
        int row = lt*16 + (lane >> 4)*4 + r;
        int c = pt*16 + (lane & 15);
        int cs = (c & 7) | ((((c >> 3) ^ (row & 7)) & 7) << 3);
        Yst[row*64 + cs] = f2bf(yacc[lt][pt][r]);
      }
  __syncthreads();
  {
    int ltl = lane >> 4, rr = lane & 15;
    int row = ltl*16 + rr;
    int lg = (w + ltl*4)*16 + rr;
    unsigned short* dst = Yb + (row0 + lg)*DINNER + hh*DHEAD;
#pragma unroll
    for (int k = 0; k < 8; ++k){
      short8 v = *(const short8*)&Yst[row*64 + ((k ^ (row & 7)) << 3)];
      *(short8*)(dst + k*8) = v;
    }
  }
}

// ---------- sequential inter-chunk recurrence; emits bf16 prev-states ----------
__launch_bounds__(256)
__global__ void state_recur_kernel(const float* __restrict__ states, const float* __restrict__ dAcs_g,
                                   unsigned short* __restrict__ prev_bf){
  const int hh = blockIdx.x, b = blockIdx.y, t = threadIdx.x;
  float S[16];
#pragma unroll
  for (int k = 0; k < 16; ++k) S[k] = 0.f;
  for (int z = 0; z < NCHUNK; ++z){
    size_t base = (((size_t)b*NCHUNK + z)*NHEADS + hh)*(DHEAD*DSTATE);
    float cd = __expf(dAcs_g[(((size_t)(b*NHEADS + hh))*NCHUNK + z)*CHUNK + CHUNK-1]);
#pragma unroll
    for (int k = 0; k < 16; ++k){
      size_t idx = base + (size_t)k*256 + t;
      float st = states[idx];
      prev_bf[idx] = f2bf(S[k]);
      S[k] = S[k]*cd + st;
    }
  }
}

// ---------- FUSED: Yo=eA*(C.prev^T) + Yd + D*X, gate with silu(z), RMSNorm -> yn ----------
__launch_bounds__(512, 2)
__global__ void chunk_fin_kernel(const unsigned short* __restrict__ X,
                                 const unsigned short* __restrict__ Cm,
                                 const unsigned short* __restrict__ zx,
                                 const float* __restrict__ dAcs_g,
                                 const unsigned short* __restrict__ prev_bf,
                                 const float* __restrict__ Dp,
                                 const unsigned short* __restrict__ Yb,
                                 const float* __restrict__ gnw,
                                 unsigned short* __restrict__ yn){
  const int s = blockIdx.x;                 // 0..255: z*16 + slice
  const int b = blockIdx.y;
  const int z = s >> 4, sl = s & 15;
  const int t = threadIdx.x, w = t >> 6, lane = t & 63;
  const size_t row0 = (size_t)b*LSEQ + z*CHUNK + sl*16;
  __shared__ __align__(16) unsigned short Yg[16][2056];   // padded: row stride 4112B
  __shared__ float seA[NHEADS][16];
  __shared__ float sDp[NHEADS];

  { // eA table: 512 threads -> 32 heads x 16 rows
    int hh = t >> 4, r = t & 15;
    seA[hh][r] = __expf(dAcs_g[(((size_t)(b*NHEADS + hh))*NCHUNK + z)*CHUNK + sl*16 + r]);
    if (t < NHEADS) sDp[t] = Dp[t];
  }
  __syncthreads();

  // A-frags: C rows row0..row0+15 (shared across all heads)
  short8 cf[2];
#pragma unroll
  for (int k2 = 0; k2 < 2; ++k2)
    cf[k2] = *(const short8*)(Cm + (row0 + (lane & 15))*DSTATE + k2*32 + (lane >> 4)*8);

  // Phase A: per wave, 4 heads; Yo = eA * C.prev^T -> Yg
  for (int hi = 0; hi < 4; ++hi){
    int hh = w*4 + hi;
    const unsigned short* pvb = prev_bf + (((size_t)b*NCHUNK + z)*NHEADS + hh)*(DHEAD*DSTATE);
    f32x4 acc[4] = {};
#pragma unroll
    for (int k2 = 0; k2 < 2; ++k2){
      int kc = k2*32 + (lane >> 4)*8;
#pragma unroll
      for (int pt = 0; pt < 4; ++pt){
        short8 bv = *(const short8*)(pvb + (size_t)(pt*16 + (lane & 15))*DSTATE + kc);
        acc[pt] = __builtin_amdgcn_mfma_f32_16x16x32_bf16(cf[k2], bv, acc[pt], 0, 0, 0);
      }
    }
#pragma unroll
    for (int pt = 0; pt < 4; ++pt){
      int c = hh*DHEAD + pt*16 + (lane & 15);
#pragma unroll
      for (int r = 0; r < 4; ++r){
        int row = (lane >> 4)*4 + r;
        Yg[row][c] = f2bf(acc[pt][r] * seA[hh][row]);
      }
    }
  }
  __syncthreads();

  // Phase B: thread (row = t>>5, i = t&31): 8 x short8 spans of 8 cols
  const int row = t >> 5, i = t & 31;
  const size_t grow = row0 + row;
  float ss = 0.f;
#pragma unroll
  for (int j = 0; j < 8; ++j){
    int c0 = i*8 + j*256;
    short8 yo = *(const short8*)&Yg[row][c0];
    short8 yd = *(const short8*)(Yb + grow*DINNER + c0);
    short8 xv = *(const short8*)(X  + grow*DINNER + c0);
    short8 zv = *(const short8*)(zx + grow*DINPROJ + c0);
    float Dh = sDp[c0 >> 6];
    short8 og;
#pragma unroll
    for (int q = 0; q < 8; ++q){
      float y = bf2f((unsigned short)yd[q]) + bf2f((unsigned short)yo[q])
              + Dh*bf2f((unsigned short)xv[q]);
      float zf = bf2f((unsigned short)zv[q]);
      float g = y * (zf / (1.f + __expf(-zf)));
      ss += g*g;
      og[q] = (short)f2bf(g);
    }
    *(short8*)&Yg[row][c0] = og;
  }
  for (int off = 16; off; off >>= 1) ss += __shfl_down(ss, off, 32);
  float sc = __shfl(ss, 0, 32);
  sc = rsqrtf(sc * (1.f/DINNER) + 1e-5f);
  __syncthreads();

  // Phase C: scaled write
#pragma unroll
  for (int j = 0; j < 8; ++j){
    int c0 = i*8 + j*256;
    short8 g = *(const short8*)&Yg[row][c0];
    f32x4 w0 = *(const f32x4*)(gnw + c0);
    f32x4 w1 = *(const f32x4*)(gnw + c0 + 4);
    short8 o;
#pragma unroll
    for (int q = 0; q < 4; ++q) o[q]   = (short)f2bf(bf2f((unsigned short)g[q])  *sc*w0[q]);
#pragma unroll
    for (int q = 0; q < 4; ++q) o[q+4] = (short)f2bf(bf2f((unsigned short)g[q+4])*sc*w1[q]);
    *(short8*)(yn + grow*DINNER + c0) = o;
  }
}

// ---------- launch ----------
extern "C" void kernel_launch(void* const* d_in, const int* in_sizes, int n_in,
                              void* d_out, int out_size, void* d_ws, size_t ws_size,
                              hipStream_t stream){
  const float* x      = (const float*)d_in[0];
  const float* in_w   = (const float*)d_in[1];
  const float* conv_w = (const float*)d_in[2];
  const float* conv_b = (const float*)d_in[3];
  const float* dt_b   = (const float*)d_in[4];
  const float* A_log  = (const float*)d_in[5];
  const float* Dp     = (const float*)d_in[6];
  const float* gnw    = (const float*)d_in[7];
  const float* out_w  = (const float*)d_in[8];
  const float* norm_w = (const float*)d_in[9];
  float* outp = (float*)d_out;

  const size_t NEEDED =
      (size_t)NROWS*DMODEL*2 + (size_t)NPAD*DMODEL*2 + (size_t)DMODEL*DINNER*2
    + (size_t)NROWS*DINPROJ*2 + (size_t)NROWS*DINNER*2 /*X*/ + (size_t)NROWS*DINNER*2 /*Yb*/
    + (size_t)NROWS*DSTATE*2*2 + (size_t)BSZ*NHEADS*LSEQ*4
    + (size_t)BSZ*NHEADS*NCHUNK*CHUNK*4
    + (size_t)BSZ*NCHUNK*NHEADS*DHEAD*DSTATE*4
    + (size_t)BSZ*NCHUNK*NHEADS*DHEAD*DSTATE*2   /* prev_bf */
    + 40*256;
  if (ws_size < NEEDED) return;   // clean fail signals ws too small

  char* p = (char*)d_ws;
  auto alloc = [&](size_t n){ char* r = p; p += (n + 255) & ~(size_t)255; return (void*)r; };
  unsigned short* h    = (unsigned short*)alloc((size_t)NROWS*DMODEL*2);
  unsigned short* wA   = (unsigned short*)alloc((size_t)NPAD*DMODEL*2);
  unsigned short* wO   = (unsigned short*)alloc((size_t)DMODEL*DINNER*2);
  unsigned short* zx   = (unsigned short*)alloc((size_t)NROWS*DINPROJ*2);
  unsigned short* X    = (unsigned short*)alloc((size_t)NROWS*DINNER*2);
  unsigned short* Yb   = (unsigned short*)alloc((size_t)NROWS*DINNER*2);
  unsigned short* Bm   = (unsigned short*)alloc((size_t)NROWS*DSTATE*2);
  unsigned short* Cm   = (unsigned short*)alloc((size_t)NROWS*DSTATE*2);
  float* dtbuf  = (float*)alloc((size_t)BSZ*NHEADS*LSEQ*4);
  float* dAcs   = (float*)alloc((size_t)BSZ*NHEADS*NCHUNK*CHUNK*4);
  float* states = (float*)alloc((size_t)BSZ*NCHUNK*NHEADS*DHEAD*DSTATE*4);
  unsigned short* prev_bf = (unsigned short*)alloc((size_t)BSZ*NCHUNK*NHEADS*DHEAD*DSTATE*2);
  unsigned short* yn = X;   // alias: all X reads in chunk_fin precede yn writes (same rows)

  for (int layer = 0; layer < 2; ++layer){
    const float* xprev = (layer == 0) ? x : outp;
    float* xnext = outp;

    cast_pad_kernel<<<(NPAD*DMODEL + 255)/256, 256, 0, stream>>>(
        in_w + (size_t)layer*DINPROJ*DMODEL, wA, DINPROJ, DMODEL, (long long)NPAD*DMODEL);
    rmsnorm_kernel<<<NROWS, 256, 0, stream>>>(xprev, norm_w + layer*DMODEL, h);
    gemm256_bt<0><<<dim3((NROWS/256)*(NPAD/256)), 512, 0, stream>>>(
        h, wA, (void*)zx, nullptr, DMODEL, DINPROJ, NPAD/256);
    conv_silu_kernel<<<((CONVDIM/8)*(NROWS/64) + 255)/256, 256, 0, stream>>>(
        zx, conv_w + (size_t)layer*CONVDIM*4, conv_b + layer*CONVDIM, X, Bm, Cm);
    dtscan_kernel<<<dim3(NCHUNK, NHEADS, BSZ), 256, 0, stream>>>(
        zx, dt_b + layer*NHEADS, A_log + layer*NHEADS, dtbuf, dAcs);
    chunk_main_kernel<<<dim3(NCHUNK, NHEADS, BSZ), 256, 0, stream>>>(
        X, Bm, Cm, dtbuf, dAcs, states, Yb);
    state_recur_kernel<<<dim3(NHEADS, BSZ), 256, 0, stream>>>(states, dAcs, prev_bf);
    chunk_fin_kernel<<<dim3(256, BSZ), 512, 0, stream>>>(
        X, Cm, zx, dAcs, prev_bf, Dp + layer*NHEADS, Yb, gnw + (size_t)layer*DINNER, yn);
    cast_pad_kernel<<<(DMODEL*DINNER + 255)/256, 256, 0, stream>>>(
        out_w + (size_t)layer*DMODEL*DINNER, wO, DMODEL, DINNER, (long long)DMODEL*DINNER);
    gemm_bt<1><<<dim3((DMODEL/128)*(NROWS/128)), 256, 0, stream>>>(
        yn, wO, (void*)xnext, xprev, DINNER, DMODEL, DMODEL/128);
  }
  (void)in_sizes; (void)n_in; (void)out_size;
}

// Round 13
// 683.178 us; speedup vs baseline: 1.0470x; 1.0470x over previous
//
#include <hip/hip_runtime.h>

// ---------- constants ----------
#define DMODEL   1024
#define DINNER   2048
#define NHEADS   32
#define DHEAD    64
#define DSTATE   64
#define CONVDIM  2176
#define DINPROJ  4256
#define LSEQ     4096
#define BSZ      2
#define NCHUNK   16
#define CHUNK    256
#define NROWS    8192      // BSZ*LSEQ
#define NPAD     4352      // 34*128, padded in_proj rows
#define XT_P     264       // LDS transpose pitch (mult of 8, 2-way banks)

typedef __attribute__((ext_vector_type(8))) short  short8;
typedef __attribute__((ext_vector_type(4))) float  f32x4;
typedef __attribute__((ext_vector_type(4))) unsigned short us4;

__device__ __forceinline__ float bf2f(unsigned short u){
  return __uint_as_float(((unsigned int)u) << 16);
}
__device__ __forceinline__ unsigned short f2bf(float f){
  unsigned int i = __float_as_uint(f);
  i += 0x7fffu + ((i >> 16) & 1u);     // round-to-nearest-even
  return (unsigned short)(i >> 16);
}

// async global->LDS, 16B per lane (dest = wave-uniform base + lane*16)
__device__ __forceinline__ void gl_lds16(const void* g, void* l){
  __builtin_amdgcn_global_load_lds(
      (const __attribute__((address_space(1))) unsigned int*)g,
      (__attribute__((address_space(3))) unsigned int*)l, 16, 0, 0);
}

// ---------- cast f32 weights -> bf16 (optionally zero-pad extra rows) ----------
__global__ void cast_pad_kernel(const float* __restrict__ src, unsigned short* __restrict__ dst,
                                int rows_src, int cols, long long total){
  long long i = (long long)blockIdx.x * 256 + threadIdx.x;
  if (i >= total) return;
  long long r = i / cols;
  dst[i] = (r < rows_src) ? f2bf(src[i]) : (unsigned short)0;
}

// ---------- RMSNorm (f32 in -> bf16 out), row = 1024 ----------
__global__ void rmsnorm_kernel(const float* __restrict__ x, const float* __restrict__ w,
                               unsigned short* __restrict__ out){
  int r = blockIdx.x, t = threadIdx.x;
  const float* xr = x + (size_t)r * DMODEL;
  float v[4]; float s = 0.f;
#pragma unroll
  for (int i = 0; i < 4; ++i){ v[i] = xr[t + i*256]; s += v[i]*v[i]; }
  __shared__ float red[4];
  for (int off = 32; off; off >>= 1) s += __shfl_down(s, off, 64);
  if ((t & 63) == 0) red[t >> 6] = s;
  __syncthreads();
  s = red[0] + red[1] + red[2] + red[3];
  float sc = rsqrtf(s * (1.f/DMODEL) + 1e-5f);
#pragma unroll
  for (int i = 0; i < 4; ++i)
    out[(size_t)r*DMODEL + t + i*256] = f2bf(v[i]*sc*w[t + i*256]);
}

// ---------- bf16 MFMA GEMM, C[i,j] = sum_k A[i,k]*B[j,k]  (m97 structure, proven) ----------
template<int EPI>
__launch_bounds__(256, 3)
__global__ void gemm_bt(const unsigned short* __restrict__ A, const unsigned short* __restrict__ Bw,
                        void* __restrict__ Cout, const float* __restrict__ Cres,
                        int K, int Nstore){
  __shared__ __align__(16) unsigned short As[128*64];
  __shared__ __align__(16) unsigned short Bs[128*64];
  const int m0 = blockIdx.y * 128, n0 = blockIdx.x * 128;
  const int t = threadIdx.x, w = t >> 6, lane = t & 63;
  const int wr = w >> 1, wc = w & 1;
  const int srow = lane >> 3;           // 0..7
  const int scol = (lane & 7) * 8;      // 0..56
  f32x4 acc[4][4] = {};

  for (int k0 = 0; k0 < K; k0 += 64){
#pragma unroll
    for (int it = 0; it < 4; ++it){
      int rr = (w*4 + it)*8 + srow;
      gl_lds16(A  + (size_t)(m0 + rr)*K + k0 + scol, &As[(w*4 + it)*512]);
      gl_lds16(Bw + (size_t)(n0 + rr)*K + k0 + scol, &Bs[(w*4 + it)*512]);
    }
    __syncthreads();
#pragma unroll
    for (int kk = 0; kk < 64; kk += 32){
      short8 af[4], bfr[4];
      int col = kk + (lane >> 4)*8;
#pragma unroll
      for (int m = 0; m < 4; ++m)
        af[m] = *(const short8*)&As[(wr*64 + m*16 + (lane & 15))*64 + col];
#pragma unroll
      for (int n = 0; n < 4; ++n)
        bfr[n] = *(const short8*)&Bs[(wc*64 + n*16 + (lane & 15))*64 + col];
#pragma unroll
      for (int m = 0; m < 4; ++m)
#pragma unroll
        for (int n = 0; n < 4; ++n)
          acc[m][n] = __builtin_amdgcn_mfma_f32_16x16x32_bf16(af[m], bfr[n], acc[m][n], 0, 0, 0);
    }
    __syncthreads();
  }

#pragma unroll
  for (int m = 0; m < 4; ++m){
#pragma unroll
    for (int n = 0; n < 4; ++n){
      int col = n0 + wc*64 + n*16 + (lane & 15);
      if (col < Nstore){
#pragma unroll
        for (int r = 0; r < 4; ++r){
          int row = m0 + wr*64 + m*16 + (lane >> 4)*4 + r;
          if (EPI == 0)
            ((unsigned short*)Cout)[(size_t)row*Nstore + col] = f2bf(acc[m][n][r]);
          else
            ((float*)Cout)[(size_t)row*Nstore + col] =
                Cres[(size_t)row*Nstore + col] + acc[m][n][r];
        }
      }
    }
  }
}

// ---------- causal conv1d (K=4) + silu, 8 channels/thread, rolling taps ----------
__global__ void conv_silu_kernel(const unsigned short* __restrict__ zx,
                                 const float* __restrict__ cw, const float* __restrict__ cb,
                                 unsigned short* __restrict__ X, unsigned short* __restrict__ Bm,
                                 unsigned short* __restrict__ Cm){
  int gid = blockIdx.x*256 + threadIdx.x;
  if (gid >= (CONVDIM/8)*(NROWS/64)) return;
  const int oc = gid % (CONVDIM/8);
  const int rb = gid / (CONVDIM/8);
  const int c = oc*8;
  const size_t r0 = (size_t)rb*64;
  const int l0 = (int)(r0 & (LSEQ-1));
  float w[4][8], bias[8];
#pragma unroll
  for (int j = 0; j < 8; ++j){
    bias[j] = cb[c+j];
#pragma unroll
    for (int i = 0; i < 4; ++i) w[i][j] = cw[(c+j)*4 + i];
  }
  const unsigned short* src = zx + DINNER + c;
  float p[3][8];
#pragma unroll
  for (int i = 0; i < 3; ++i){
    if (l0 - 3 + i >= 0){
      short8 v = *(const short8*)(src + (r0 - 3 + i)*DINPROJ);
#pragma unroll
      for (int j = 0; j < 8; ++j) p[i][j] = bf2f((unsigned short)v[j]);
    } else {
#pragma unroll
      for (int j = 0; j < 8; ++j) p[i][j] = 0.f;
    }
  }
  for (int it = 0; it < 64; ++it){
    const size_t r = r0 + it;
    short8 v = *(const short8*)(src + r*DINPROJ);
    float cur[8];
    short8 ov;
#pragma unroll
    for (int j = 0; j < 8; ++j){
      cur[j] = bf2f((unsigned short)v[j]);
      float a = bias[j] + w[0][j]*p[0][j] + w[1][j]*p[1][j] + w[2][j]*p[2][j] + w[3][j]*cur[j];
      float s = a / (1.f + __expf(-a));
      ov[j] = (short)f2bf(s);
    }
    if (c < DINNER)             *(short8*)(X  + r*DINNER + c) = ov;
    else if (c < DINNER+DSTATE) *(short8*)(Bm + r*DSTATE + (c-DINNER)) = ov;
    else                        *(short8*)(Cm + r*DSTATE + (c-DINNER-DSTATE)) = ov;
#pragma unroll
    for (int j = 0; j < 8; ++j){ p[0][j]=p[1][j]; p[1][j]=p[2][j]; p[2][j]=cur[j]; }
  }
}

// ---------- dt softplus + per-chunk inclusive cumsum of dA ----------
__global__ void dtscan_kernel(const unsigned short* __restrict__ zx, const float* __restrict__ dtb,
                              const float* __restrict__ A_log,
                              float* __restrict__ dt_sp, float* __restrict__ dAcs_g){
  const int z = blockIdx.x, hh = blockIdx.y, b = blockIdx.z;
  const int t = threadIdx.x;
  __shared__ float sdA[CHUNK];
  const float Ah = -__expf(A_log[hh]);
  size_t r = (size_t)b*LSEQ + z*CHUNK + t;
  float raw = bf2f(zx[r*DINPROJ + DINNER + CONVDIM + hh]) + dtb[hh];
  float dtv = raw > 20.f ? raw : log1pf(__expf(raw));
  sdA[t] = dtv * Ah;
  __syncthreads();
  for (int off = 1; off < CHUNK; off <<= 1){
    float v = (t >= off) ? sdA[t - off] : 0.f;
    __syncthreads();
    sdA[t] += v;
    __syncthreads();
  }
  size_t hb = (size_t)(b*NHEADS + hh);
  dt_sp[hb*LSEQ + z*CHUNK + t] = dtv;
  dAcs_g[(hb*NCHUNK + z)*CHUNK + t] = sdA[t];
}

// ---------- G = C . B^T per (b,z): head-independent Gram matrix, bf16 ----------
// grid (NCHUNK*4, BSZ): block = 64 G-rows; 4 waves each own a 64-col group.
__launch_bounds__(256, 4)
__global__ void gram_kernel(const unsigned short* __restrict__ Bm,
                            const unsigned short* __restrict__ Cm,
                            unsigned short* __restrict__ Gb){
  const int zq = blockIdx.x, b = blockIdx.y;
  const int z = zq >> 2, rq = zq & 3;
  const int t = threadIdx.x, w = t >> 6, lane = t & 63;
  const size_t row0 = (size_t)b*LSEQ + z*CHUNK;
  f32x4 acc[4][4] = {};
#pragma unroll
  for (int k2 = 0; k2 < 2; ++k2){
    int kc = k2*32 + (lane >> 4)*8;
    short8 cf[4], bfr[4];
#pragma unroll
    for (int mf = 0; mf < 4; ++mf)
      cf[mf] = *(const short8*)(Cm + (row0 + rq*64 + mf*16 + (lane & 15))*DSTATE + kc);
#pragma unroll
    for (int nf = 0; nf < 4; ++nf)
      bfr[nf] = *(const short8*)(Bm + (row0 + w*64 + nf*16 + (lane & 15))*DSTATE + kc);
#pragma unroll
    for (int mf = 0; mf < 4; ++mf)
#pragma unroll
      for (int nf = 0; nf < 4; ++nf)
        acc[mf][nf] = __builtin_amdgcn_mfma_f32_16x16x32_bf16(cf[mf], bfr[nf], acc[mf][nf], 0, 0, 0);
  }
  unsigned short* Gp = Gb + (((size_t)b*NCHUNK + z) << 16);
#pragma unroll
  for (int mf = 0; mf < 4; ++mf)
#pragma unroll
    for (int nf = 0; nf < 4; ++nf)
#pragma unroll
      for (int r = 0; r < 4; ++r){
        int row = rq*64 + mf*16 + (lane >> 4)*4 + r;
        int col = w*64 + nf*16 + (lane & 15);
        Gp[(size_t)row*256 + col] = f2bf(acc[mf][nf][r]);
      }
}

// ---------- per-(b,chunk,head): states + within-chunk Yd (G precomputed) ----------
__launch_bounds__(256, 2)
__global__ void chunk_main_kernel(const unsigned short* __restrict__ X,
                                  const unsigned short* __restrict__ Bm,
                                  const unsigned short* __restrict__ Gb,
                                  const float* __restrict__ dt_sp,
                                  const float* __restrict__ dAcs_g,
                                  float* __restrict__ states,
                                  unsigned short* __restrict__ Yb){
  const int z = blockIdx.x, hh = blockIdx.y, b = blockIdx.z;
  const int t = threadIdx.x, w = t >> 6, lane = t & 63;
  __shared__ __align__(16) unsigned short Xt[64 * XT_P];   // Xdt^T [p][l]
  __shared__ __align__(16) unsigned short U[64 * XT_P];    // union: Btdec -> Ystage
  __shared__ float sdA[CHUNK];
  __shared__ float sdt[CHUNK];

  const size_t row0 = (size_t)b*LSEQ + z*CHUNK;
  const size_t hb = (size_t)(b*NHEADS + hh);
  sdA[t] = dAcs_g[(hb*NCHUNK + z)*CHUNK + t];
  sdt[t] = dt_sp[hb*LSEQ + z*CHUNK + t];
  __syncthreads();
  const float total = sdA[CHUNK-1];

  // stage Xt[p][l] = X[l][p]*dt[l], U=Btdec[n][l] = B[l][n]*exp(total-sdA[l])
  for (int it = 0; it < 16; ++it){
    int l = it*16 + (t >> 4);
    int p4 = (t & 15) * 4;
    float dtl = sdt[l];
    float dec = __expf(total - sdA[l]);
    us4 xv = *(const us4*)(X  + (row0 + l)*DINNER + hh*DHEAD + p4);
    us4 bv = *(const us4*)(Bm + (row0 + l)*DSTATE + p4);
#pragma unroll
    for (int j = 0; j < 4; ++j){
      Xt[(p4 + j)*XT_P + l] = f2bf(bf2f(xv[j]) * dtl);
      U [(p4 + j)*XT_P + l] = f2bf(bf2f(bv[j]) * dec);
    }
  }
  __syncthreads();

  // ---- states: D[n][p] = sum_l Btdec[n][l] * Xt[p][l]; wave w owns n-tile w
  {
    f32x4 sacc[4] = {};
    for (int k2 = 0; k2 < 8; ++k2){
      int kc = k2*32 + (lane >> 4)*8;
      short8 a = *(const short8*)&U[(w*16 + (lane & 15))*XT_P + kc];
#pragma unroll
      for (int pt = 0; pt < 4; ++pt){
        short8 bfr = *(const short8*)&Xt[(pt*16 + (lane & 15))*XT_P + kc];
        sacc[pt] = __builtin_amdgcn_mfma_f32_16x16x32_bf16(a, bfr, sacc[pt], 0, 0, 0);
      }
    }
    float* sp = states + (((size_t)b*NCHUNK + z)*NHEADS + hh)*(DHEAD*DSTATE);
#pragma unroll
    for (int pt = 0; pt < 4; ++pt){
      int p = pt*16 + (lane & 15);
#pragma unroll
      for (int r = 0; r < 4; ++r){
        int n = w*16 + (lane >> 4)*4 + r;
        sp[p*DSTATE + n] = sacc[pt][r];
      }
    }
  }
  __syncthreads();   // all waves done reading U (Btdec)

  // ---- Yd: wave w owns l-tiles {w, w+4, w+8, w+12}; masked G in-register ----
  const unsigned short* Gp = Gb + (((size_t)b*NCHUNK + z) << 16);
  f32x4 yacc[4][4] = {};
  for (int st = 0; st < 8; ++st){
    short8 xb[4];
#pragma unroll
    for (int pt = 0; pt < 4; ++pt)
      xb[pt] = *(const short8*)&Xt[(pt*16 + (lane & 15))*XT_P + st*32 + (lane >> 4)*8];
    const int s0 = st*32 + (lane >> 4)*8;
    float es[8];
#pragma unroll
    for (int j = 0; j < 8; ++j) es[j] = sdA[s0 + j];
#pragma unroll
    for (int lt = 0; lt < 4; ++lt){
      int lg = w + lt*4;
      if (st*32 > lg*16 + 15) continue;          // s-tile fully above diagonal
      int l = lg*16 + (lane & 15);
      float el = sdA[l];
      short8 gv = *(const short8*)&Gp[(size_t)l*256 + s0];
      short8 mf;
#pragma unroll
      for (int j = 0; j < 8; ++j){
        float m = (s0 + j <= l) ? bf2f((unsigned short)gv[j]) * __expf(el - es[j]) : 0.f;
        mf[j] = (short)f2bf(m);
      }
#pragma unroll
      for (int pt = 0; pt < 4; ++pt)
        yacc[lt][pt] = __builtin_amdgcn_mfma_f32_16x16x32_bf16(mf, xb[pt], yacc[lt][pt], 0, 0, 0);
    }
  }
  __syncthreads();   // U becomes Ystage

  // ---- stage Y (bf16, XOR-swizzled 8-elem blocks) and write out coalesced
  unsigned short* Yst = U + w * 4096;
#pragma unroll
  for (int lt = 0; lt < 4; ++lt)
#pragma unroll
    for (int pt = 0; pt < 4; ++pt)
#pragma unroll
      for (int r = 0; r < 4; ++r){
        int row = lt*16 + (lane >> 4)*4 + r;
        int c = pt*16 + (lane & 15);
        int cs = (c & 7) | ((((c >> 3) ^ (row & 7)) & 7) << 3);
        Yst[row*64 + cs] = f2bf(yacc[lt][pt][r]);
      }
  __syncthreads();
  {
    int ltl = lane >> 4, rr = lane & 15;
    int row = ltl*16 + rr;
    int lg = (w + ltl*4)*16 + rr;
    unsigned short* dst = Yb + (row0 + lg)*DINNER + hh*DHEAD;
#pragma unroll
    for (int k = 0; k < 8; ++k){
      short8 v = *(const short8*)&Yst[row*64 + ((k ^ (row & 7)) << 3)];
      *(short8*)(dst + k*8) = v;
    }
  }
}

// ---------- sequential inter-chunk recurrence; emits bf16 prev-states ----------
__launch_bounds__(256)
__global__ void state_recur_kernel(const float* __restrict__ states, const float* __restrict__ dAcs_g,
                                   unsigned short* __restrict__ prev_bf){
  const int hh = blockIdx.x, b = blockIdx.y, t = threadIdx.x;
  float S[16];
#pragma unroll
  for (int k = 0; k < 16; ++k) S[k] = 0.f;
  for (int z = 0; z < NCHUNK; ++z){
    size_t base = (((size_t)b*NCHUNK + z)*NHEADS + hh)*(DHEAD*DSTATE);
    float cd = __expf(dAcs_g[(((size_t)(b*NHEADS + hh))*NCHUNK + z)*CHUNK + CHUNK-1]);
#pragma unroll
    for (int k = 0; k < 16; ++k){
      size_t idx = base + (size_t)k*256 + t;
      float st = states[idx];
      prev_bf[idx] = f2bf(S[k]);
      S[k] = S[k]*cd + st;
    }
  }
}

// ---------- FUSED: Yo=eA*(C.prev^T) + Yd + D*X, gate with silu(z), RMSNorm -> yn ----------
__launch_bounds__(512, 2)
__global__ void chunk_fin_kernel(const unsigned short* __restrict__ X,
                                 const unsigned short* __restrict__ Cm,
                                 const unsigned short* __restrict__ zx,
                                 const float* __restrict__ dAcs_g,
                                 const unsigned short* __restrict__ prev_bf,
                                 const float* __restrict__ Dp,
                                 const unsigned short* __restrict__ Yb,
                                 const float* __restrict__ gnw,
                                 unsigned short* __restrict__ yn){
  const int s = blockIdx.x;                 // 0..255: z*16 + slice
  const int b = blockIdx.y;
  const int z = s >> 4, sl = s & 15;
  const int t = threadIdx.x, w = t >> 6, lane = t & 63;
  const size_t row0 = (size_t)b*LSEQ + z*CHUNK + sl*16;
  __shared__ __align__(16) unsigned short Yg[16][2056];   // padded: row stride 4112B
  __shared__ float seA[NHEADS][16];
  __shared__ float sDp[NHEADS];

  { // eA table: 512 threads -> 32 heads x 16 rows
    int hh = t >> 4, r = t & 15;
    seA[hh][r] = __expf(dAcs_g[(((size_t)(b*NHEADS + hh))*NCHUNK + z)*CHUNK + sl*16 + r]);
    if (t < NHEADS) sDp[t] = Dp[t];
  }
  __syncthreads();

  // A-frags: C rows row0..row0+15 (shared across all heads)
  short8 cf[2];
#pragma unroll
  for (int k2 = 0; k2 < 2; ++k2)
    cf[k2] = *(const short8*)(Cm + (row0 + (lane & 15))*DSTATE + k2*32 + (lane >> 4)*8);

  // Phase A: per wave, 4 heads; Yo = eA * C.prev^T -> Yg
  for (int hi = 0; hi < 4; ++hi){
    int hh = w*4 + hi;
    const unsigned short* pvb = prev_bf + (((size_t)b*NCHUNK + z)*NHEADS + hh)*(DHEAD*DSTATE);
    f32x4 acc[4] = {};
#pragma unroll
    for (int k2 = 0; k2 < 2; ++k2){
      int kc = k2*32 + (lane >> 4)*8;
#pragma unroll
      for (int pt = 0; pt < 4; ++pt){
        short8 bv = *(const short8*)(pvb + (size_t)(pt*16 + (lane & 15))*DSTATE + kc);
        acc[pt] = __builtin_amdgcn_mfma_f32_16x16x32_bf16(cf[k2], bv, acc[pt], 0, 0, 0);
      }
    }
#pragma unroll
    for (int pt = 0; pt < 4; ++pt){
      int c = hh*DHEAD + pt*16 + (lane & 15);
#pragma unroll
      for (int r = 0; r < 4; ++r){
        int row = (lane >> 4)*4 + r;
        Yg[row][c] = f2bf(acc[pt][r] * seA[hh][row]);
      }
    }
  }
  __syncthreads();

  // Phase B: thread (row = t>>5, i = t&31): 8 x short8 spans of 8 cols
  const int row = t >> 5, i = t & 31;
  const size_t grow = row0 + row;
  float ss = 0.f;
#pragma unroll
  for (int j = 0; j < 8; ++j){
    int c0 = i*8 + j*256;
    short8 yo = *(const short8*)&Yg[row][c0];
    short8 yd = *(const short8*)(Yb + grow*DINNER + c0);
    short8 xv = *(const short8*)(X  + grow*DINNER + c0);
    short8 zv = *(const short8*)(zx + grow*DINPROJ + c0);
    float Dh = sDp[c0 >> 6];
    short8 og;
#pragma unroll
    for (int q = 0; q < 8; ++q){
      float y = bf2f((unsigned short)yd[q]) + bf2f((unsigned short)yo[q])
              + Dh*bf2f((unsigned short)xv[q]);
      float zf = bf2f((unsigned short)zv[q]);
      float g = y * (zf / (1.f + __expf(-zf)));
      ss += g*g;
      og[q] = (short)f2bf(g);
    }
    *(short8*)&Yg[row][c0] = og;
  }
  for (int off = 16; off; off >>= 1) ss += __shfl_down(ss, off, 32);
  float sc = __shfl(ss, 0, 32);
  sc = rsqrtf(sc * (1.f/DINNER) + 1e-5f);
  __syncthreads();

  // Phase C: scaled write
#pragma unroll
  for (int j = 0; j < 8; ++j){
    int c0 = i*8 + j*256;
    short8 g = *(const short8*)&Yg[row][c0];
    f32x4 w0 = *(const f32x4*)(gnw + c0);
    f32x4 w1 = *(const f32x4*)(gnw + c0 + 4);
    short8 o;
#pragma unroll
    for (int q = 0; q < 4; ++q) o[q]   = (short)f2bf(bf2f((unsigned short)g[q])  *sc*w0[q]);
#pragma unroll
    for (int q = 0; q < 4; ++q) o[q+4] = (short)f2bf(bf2f((unsigned short)g[q+4])*sc*w1[q]);
    *(short8*)(yn + grow*DINNER + c0) = o;
  }
}

// ---------- launch ----------
extern "C" void kernel_launch(void* const* d_in, const int* in_sizes, int n_in,
                              void* d_out, int out_size, void* d_ws, size_t ws_size,
                              hipStream_t stream){
  const float* x      = (const float*)d_in[0];
  const float* in_w   = (const float*)d_in[1];
  const float* conv_w = (const float*)d_in[2];
  const float* conv_b = (const float*)d_in[3];
  const float* dt_b   = (const float*)d_in[4];
  const float* A_log  = (const float*)d_in[5];
  const float* Dp     = (const float*)d_in[6];
  const float* gnw    = (const float*)d_in[7];
  const float* out_w  = (const float*)d_in[8];
  const float* norm_w = (const float*)d_in[9];
  float* outp = (float*)d_out;

  const size_t NEEDED =
      (size_t)NROWS*DMODEL*2 + (size_t)NPAD*DMODEL*2 + (size_t)DMODEL*DINNER*2
    + (size_t)NROWS*DINPROJ*2 + (size_t)NROWS*DINNER*2 /*X*/ + (size_t)NROWS*DINNER*2 /*Yb*/
    + (size_t)NROWS*DSTATE*2*2 + (size_t)BSZ*NHEADS*LSEQ*4
    + (size_t)BSZ*NHEADS*NCHUNK*CHUNK*4
    + (size_t)BSZ*NCHUNK*NHEADS*DHEAD*DSTATE*4
    + (size_t)BSZ*NCHUNK*NHEADS*DHEAD*DSTATE*2   /* prev_bf */
    + (size_t)BSZ*NCHUNK*CHUNK*CHUNK*2           /* Gb */
    + 48*256;
  if (ws_size < NEEDED) return;   // clean fail signals ws too small

  char* p = (char*)d_ws;
  auto alloc = [&](size_t n){ char* r = p; p += (n + 255) & ~(size_t)255; return (void*)r; };
  unsigned short* h    = (unsigned short*)alloc((size_t)NROWS*DMODEL*2);
  unsigned short* wA   = (unsigned short*)alloc((size_t)NPAD*DMODEL*2);
  unsigned short* wO   = (unsigned short*)alloc((size_t)DMODEL*DINNER*2);
  unsigned short* zx   = (unsigned short*)alloc((size_t)NROWS*DINPROJ*2);
  unsigned short* X    = (unsigned short*)alloc((size_t)NROWS*DINNER*2);
  unsigned short* Yb   = (unsigned short*)alloc((size_t)NROWS*DINNER*2);
  unsigned short* Bm   = (unsigned short*)alloc((size_t)NROWS*DSTATE*2);
  unsigned short* Cm   = (unsigned short*)alloc((size_t)NROWS*DSTATE*2);
  float* dtbuf  = (float*)alloc((size_t)BSZ*NHEADS*LSEQ*4);
  float* dAcs   = (float*)alloc((size_t)BSZ*NHEADS*NCHUNK*CHUNK*4);
  float* states = (float*)alloc((size_t)BSZ*NCHUNK*NHEADS*DHEAD*DSTATE*4);
  unsigned short* prev_bf = (unsigned short*)alloc((size_t)BSZ*NCHUNK*NHEADS*DHEAD*DSTATE*2);
  unsigned short* Gb = (unsigned short*)alloc((size_t)BSZ*NCHUNK*CHUNK*CHUNK*2);
  unsigned short* yn = X;   // alias: all X reads in chunk_fin precede yn writes (same rows)

  for (int layer = 0; layer < 2; ++layer){
    const float* xprev = (layer == 0) ? x : outp;
    float* xnext = outp;

    cast_pad_kernel<<<(NPAD*DMODEL + 255)/256, 256, 0, stream>>>(
        in_w + (size_t)layer*DINPROJ*DMODEL, wA, DINPROJ, DMODEL, (long long)NPAD*DMODEL);
    rmsnorm_kernel<<<NROWS, 256, 0, stream>>>(xprev, norm_w + layer*DMODEL, h);
    gemm_bt<0><<<dim3(NPAD/128, NROWS/128), 256, 0, stream>>>(
        h, wA, (void*)zx, nullptr, DMODEL, DINPROJ);
    conv_silu_kernel<<<((CONVDIM/8)*(NROWS/64) + 255)/256, 256, 0, stream>>>(
        zx, conv_w + (size_t)layer*CONVDIM*4, conv_b + layer*CONVDIM, X, Bm, Cm);
    dtscan_kernel<<<dim3(NCHUNK, NHEADS, BSZ), 256, 0, stream>>>(
        zx, dt_b + layer*NHEADS, A_log + layer*NHEADS, dtbuf, dAcs);
    gram_kernel<<<dim3(NCHUNK*4, BSZ), 256, 0, stream>>>(Bm, Cm, Gb);
    chunk_main_kernel<<<dim3(NCHUNK, NHEADS, BSZ), 256, 0, stream>>>(
        X, Bm, Gb, dtbuf, dAcs, states, Yb);
    state_recur_kernel<<<dim3(NHEADS, BSZ), 256, 0, stream>>>(states, dAcs, prev_bf);
    chunk_fin_kernel<<<dim3(256, BSZ), 512, 0, stream>>>(
        X, Cm, zx, dAcs, prev_bf, Dp + layer*NHEADS, Yb, gnw + (size_t)layer*DINNER, yn);
    cast_pad_kernel<<<(DMODEL*DINNER + 255)/256, 256, 0, stream>>>(
        out_w + (size_t)layer*DMODEL*DINNER, wO, DMODEL, DINNER, (long long)DMODEL*DINNER);
    gemm_bt<1><<<dim3(DMODEL/128, NROWS/128), 256, 0, stream>>>(
        yn, wO, (void*)xnext, xprev, DINNER, DMODEL);
  }
  (void)in_sizes; (void)n_in; (void)out_size;
}

// Round 14
// 677.781 us; speedup vs baseline: 1.0553x; 1.0080x over previous
//
#include <hip/hip_runtime.h>

// ---------- constants ----------
#define DMODEL   1024
#define DINNER   2048
#define NHEADS   32
#define DHEAD    64
#define DSTATE   64
#define CONVDIM  2176
#define DINPROJ  4256
#define LSEQ     4096
#define BSZ      2
#define NCHUNK   16
#define CHUNK    256
#define NROWS    8192      // BSZ*LSEQ
#define NPAD     4352      // 34*128, padded in_proj rows
#define XT_P     264       // LDS transpose pitch (mult of 8, 2-way banks)

typedef __attribute__((ext_vector_type(8))) short  short8;
typedef __attribute__((ext_vector_type(4))) float  f32x4;
typedef __attribute__((ext_vector_type(4))) unsigned short us4;

__device__ __forceinline__ float bf2f(unsigned short u){
  return __uint_as_float(((unsigned int)u) << 16);
}
__device__ __forceinline__ unsigned short f2bf(float f){
  unsigned int i = __float_as_uint(f);
  i += 0x7fffu + ((i >> 16) & 1u);     // round-to-nearest-even
  return (unsigned short)(i >> 16);
}

// async global->LDS, 16B per lane (dest = wave-uniform base + lane*16)
__device__ __forceinline__ void gl_lds16(const void* g, void* l){
  __builtin_amdgcn_global_load_lds(
      (const __attribute__((address_space(1))) unsigned int*)g,
      (__attribute__((address_space(3))) unsigned int*)l, 16, 0, 0);
}

// ---------- cast ALL weights (both layers) -> bf16 once ----------
__global__ void cast_all_kernel(const float* __restrict__ in_w, const float* __restrict__ out_w,
                                unsigned short* __restrict__ wA, unsigned short* __restrict__ wO){
  const long long nA = (long long)2*NPAD*DMODEL;
  const long long nO = (long long)2*DMODEL*DINNER;
  long long i = (long long)blockIdx.x*256 + threadIdx.x;
  if (i < nA){
    long long layer = i / ((long long)NPAD*DMODEL);
    long long j = i - layer*((long long)NPAD*DMODEL);
    long long r = j / DMODEL;
    wA[i] = (r < DINPROJ)
        ? f2bf(in_w[layer*((long long)DINPROJ*DMODEL) + r*DMODEL + (j - r*DMODEL)])
        : (unsigned short)0;
  } else if (i < nA + nO){
    long long k = i - nA;
    wO[k] = f2bf(out_w[k]);
  }
}

// ---------- RMSNorm: wave-per-row, shuffle-only (f32 in -> bf16 out) ----------
__launch_bounds__(256)
__global__ void rmsnorm_kernel(const float* __restrict__ x, const float* __restrict__ w,
                               unsigned short* __restrict__ out){
  const int r = blockIdx.x*4 + (threadIdx.x >> 6);
  const int lane = threadIdx.x & 63;
  const float* xr = x + (size_t)r*DMODEL;
  f32x4 v[4]; float s = 0.f;
#pragma unroll
  for (int i = 0; i < 4; ++i){
    v[i] = *(const f32x4*)(xr + lane*4 + i*256);
#pragma unroll
    for (int j = 0; j < 4; ++j) s += v[i][j]*v[i][j];
  }
  for (int off = 32; off; off >>= 1) s += __shfl_down(s, off, 64);
  s = __shfl(s, 0, 64);
  const float sc = rsqrtf(s*(1.f/DMODEL) + 1e-5f);
#pragma unroll
  for (int i = 0; i < 4; ++i){
    us4 o;
    const float* wp = w + lane*4 + i*256;
#pragma unroll
    for (int j = 0; j < 4; ++j) o[j] = f2bf(v[i][j]*sc*wp[j]);
    *(us4*)(out + (size_t)r*DMODEL + lane*4 + i*256) = o;
  }
}

// ---------- bf16 MFMA GEMM, C[i,j] = sum_k A[i,k]*B[j,k]  (m97 structure, proven) ----------
template<int EPI>
__launch_bounds__(256, 3)
__global__ void gemm_bt(const unsigned short* __restrict__ A, const unsigned short* __restrict__ Bw,
                        void* __restrict__ Cout, const float* __restrict__ Cres,
                        int K, int Nstore){
  __shared__ __align__(16) unsigned short As[128*64];
  __shared__ __align__(16) unsigned short Bs[128*64];
  const int m0 = blockIdx.y * 128, n0 = blockIdx.x * 128;
  const int t = threadIdx.x, w = t >> 6, lane = t & 63;
  const int wr = w >> 1, wc = w & 1;
  const int srow = lane >> 3;           // 0..7
  const int scol = (lane & 7) * 8;      // 0..56
  f32x4 acc[4][4] = {};

  for (int k0 = 0; k0 < K; k0 += 64){
#pragma unroll
    for (int it = 0; it < 4; ++it){
      int rr = (w*4 + it)*8 + srow;
      gl_lds16(A  + (size_t)(m0 + rr)*K + k0 + scol, &As[(w*4 + it)*512]);
      gl_lds16(Bw + (size_t)(n0 + rr)*K + k0 + scol, &Bs[(w*4 + it)*512]);
    }
    __syncthreads();
#pragma unroll
    for (int kk = 0; kk < 64; kk += 32){
      short8 af[4], bfr[4];
      int col = kk + (lane >> 4)*8;
#pragma unroll
      for (int m = 0; m < 4; ++m)
        af[m] = *(const short8*)&As[(wr*64 + m*16 + (lane & 15))*64 + col];
#pragma unroll
      for (int n = 0; n < 4; ++n)
        bfr[n] = *(const short8*)&Bs[(wc*64 + n*16 + (lane & 15))*64 + col];
#pragma unroll
      for (int m = 0; m < 4; ++m)
#pragma unroll
        for (int n = 0; n < 4; ++n)
          acc[m][n] = __builtin_amdgcn_mfma_f32_16x16x32_bf16(af[m], bfr[n], acc[m][n], 0, 0, 0);
    }
    __syncthreads();
  }

#pragma unroll
  for (int m = 0; m < 4; ++m){
#pragma unroll
    for (int n = 0; n < 4; ++n){
      int col = n0 + wc*64 + n*16 + (lane & 15);
      if (col < Nstore){
#pragma unroll
        for (int r = 0; r < 4; ++r){
          int row = m0 + wr*64 + m*16 + (lane >> 4)*4 + r;
          if (EPI == 0)
            ((unsigned short*)Cout)[(size_t)row*Nstore + col] = f2bf(acc[m][n][r]);
          else
            ((float*)Cout)[(size_t)row*Nstore + col] =
                Cres[(size_t)row*Nstore + col] + acc[m][n][r];
        }
      }
    }
  }
}

// ---------- causal conv1d (K=4) + silu, 8 channels/thread, rolling taps ----------
__global__ void conv_silu_kernel(const unsigned short* __restrict__ zx,
                                 const float* __restrict__ cw, const float* __restrict__ cb,
                                 unsigned short* __restrict__ X, unsigned short* __restrict__ Bm,
                                 unsigned short* __restrict__ Cm){
  int gid = blockIdx.x*256 + threadIdx.x;
  if (gid >= (CONVDIM/8)*(NROWS/64)) return;
  const int oc = gid % (CONVDIM/8);
  const int rb = gid / (CONVDIM/8);
  const int c = oc*8;
  const size_t r0 = (size_t)rb*64;
  const int l0 = (int)(r0 & (LSEQ-1));
  float w[4][8], bias[8];
#pragma unroll
  for (int j = 0; j < 8; ++j){
    bias[j] = cb[c+j];
#pragma unroll
    for (int i = 0; i < 4; ++i) w[i][j] = cw[(c+j)*4 + i];
  }
  const unsigned short* src = zx + DINNER + c;
  float p[3][8];
#pragma unroll
  for (int i = 0; i < 3; ++i){
    if (l0 - 3 + i >= 0){
      short8 v = *(const short8*)(src + (r0 - 3 + i)*DINPROJ);
#pragma unroll
      for (int j = 0; j < 8; ++j) p[i][j] = bf2f((unsigned short)v[j]);
    } else {
#pragma unroll
      for (int j = 0; j < 8; ++j) p[i][j] = 0.f;
    }
  }
  for (int it = 0; it < 64; ++it){
    const size_t r = r0 + it;
    short8 v = *(const short8*)(src + r*DINPROJ);
    float cur[8];
    short8 ov;
#pragma unroll
    for (int j = 0; j < 8; ++j){
      cur[j] = bf2f((unsigned short)v[j]);
      float a = bias[j] + w[0][j]*p[0][j] + w[1][j]*p[1][j] + w[2][j]*p[2][j] + w[3][j]*cur[j];
      float s = a / (1.f + __expf(-a));
      ov[j] = (short)f2bf(s);
    }
    if (c < DINNER)             *(short8*)(X  + r*DINNER + c) = ov;
    else if (c < DINNER+DSTATE) *(short8*)(Bm + r*DSTATE + (c-DINNER)) = ov;
    else                        *(short8*)(Cm + r*DSTATE + (c-DINNER-DSTATE)) = ov;
#pragma unroll
    for (int j = 0; j < 8; ++j){ p[0][j]=p[1][j]; p[1][j]=p[2][j]; p[2][j]=cur[j]; }
  }
}

// ---------- dt softplus + per-chunk inclusive cumsum (wave shfl scan) ----------
__global__ void dtscan_kernel(const unsigned short* __restrict__ zx, const float* __restrict__ dtb,
                              const float* __restrict__ A_log,
                              float* __restrict__ dt_sp, float* __restrict__ dAcs_g){
  const int z = blockIdx.x, hh = blockIdx.y, b = blockIdx.z;
  const int t = threadIdx.x, w = t >> 6, lane = t & 63;
  __shared__ float wsum[4];
  const float Ah = -__expf(A_log[hh]);
  size_t r = (size_t)b*LSEQ + z*CHUNK + t;
  float raw = bf2f(zx[r*DINPROJ + DINNER + CONVDIM + hh]) + dtb[hh];
  float dtv = raw > 20.f ? raw : log1pf(__expf(raw));
  float v = dtv * Ah;
#pragma unroll
  for (int off = 1; off < 64; off <<= 1){
    float u = __shfl_up(v, off, 64);
    if (lane >= off) v += u;
  }
  if (lane == 63) wsum[w] = v;
  __syncthreads();
  float pre = 0.f;
#pragma unroll
  for (int j = 0; j < 3; ++j) if (j < w) pre += wsum[j];
  v += pre;
  size_t hb = (size_t)(b*NHEADS + hh);
  dt_sp[hb*LSEQ + z*CHUNK + t] = dtv;
  dAcs_g[(hb*NCHUNK + z)*CHUNK + t] = v;
}

// ---------- G = C . B^T per (b,z): head-independent Gram matrix, bf16 ----------
__launch_bounds__(256, 4)
__global__ void gram_kernel(const unsigned short* __restrict__ Bm,
                            const unsigned short* __restrict__ Cm,
                            unsigned short* __restrict__ Gb){
  const int zq = blockIdx.x, b = blockIdx.y;
  const int z = zq >> 2, rq = zq & 3;
  const int t = threadIdx.x, w = t >> 6, lane = t & 63;
  const size_t row0 = (size_t)b*LSEQ + z*CHUNK;
  f32x4 acc[4][4] = {};
#pragma unroll
  for (int k2 = 0; k2 < 2; ++k2){
    int kc = k2*32 + (lane >> 4)*8;
    short8 cf[4], bfr[4];
#pragma unroll
    for (int mf = 0; mf < 4; ++mf)
      cf[mf] = *(const short8*)(Cm + (row0 + rq*64 + mf*16 + (lane & 15))*DSTATE + kc);
#pragma unroll
    for (int nf = 0; nf < 4; ++nf)
      bfr[nf] = *(const short8*)(Bm + (row0 + w*64 + nf*16 + (lane & 15))*DSTATE + kc);
#pragma unroll
    for (int mf = 0; mf < 4; ++mf)
#pragma unroll
      for (int nf = 0; nf < 4; ++nf)
        acc[mf][nf] = __builtin_amdgcn_mfma_f32_16x16x32_bf16(cf[mf], bfr[nf], acc[mf][nf], 0, 0, 0);
  }
  unsigned short* Gp = Gb + (((size_t)b*NCHUNK + z) << 16);
#pragma unroll
  for (int mf = 0; mf < 4; ++mf)
#pragma unroll
    for (int nf = 0; nf < 4; ++nf)
#pragma unroll
      for (int r = 0; r < 4; ++r){
        int row = rq*64 + mf*16 + (lane >> 4)*4 + r;
        int col = w*64 + nf*16 + (lane & 15);
        Gp[(size_t)row*256 + col] = f2bf(acc[mf][nf][r]);
      }
}

// ---------- per-(b,chunk,head): states + within-chunk Yd (G precomputed) ----------
__launch_bounds__(256, 2)
__global__ void chunk_main_kernel(const unsigned short* __restrict__ X,
                                  const unsigned short* __restrict__ Bm,
                                  const unsigned short* __restrict__ Gb,
                                  const float* __restrict__ dt_sp,
                                  const float* __restrict__ dAcs_g,
                                  float* __restrict__ states,
                                  unsigned short* __restrict__ Yb){
  const int z = blockIdx.x, hh = blockIdx.y, b = blockIdx.z;
  const int t = threadIdx.x, w = t >> 6, lane = t & 63;
  __shared__ __align__(16) unsigned short Xt[64 * XT_P];   // Xdt^T [p][l]
  __shared__ __align__(16) unsigned short U[64 * XT_P];    // union: Btdec -> Ystage
  __shared__ float sdA[CHUNK];
  __shared__ float sdt[CHUNK];

  const size_t row0 = (size_t)b*LSEQ + z*CHUNK;
  const size_t hb = (size_t)(b*NHEADS + hh);
  sdA[t] = dAcs_g[(hb*NCHUNK + z)*CHUNK + t];
  sdt[t] = dt_sp[hb*LSEQ + z*CHUNK + t];
  __syncthreads();
  const float total = sdA[CHUNK-1];

  for (int it = 0; it < 16; ++it){
    int l = it*16 + (t >> 4);
    int p4 = (t & 15) * 4;
    float dtl = sdt[l];
    float dec = __expf(total - sdA[l]);
    us4 xv = *(const us4*)(X  + (row0 + l)*DINNER + hh*DHEAD + p4);
    us4 bv = *(const us4*)(Bm + (row0 + l)*DSTATE + p4);
#pragma unroll
    for (int j = 0; j < 4; ++j){
      Xt[(p4 + j)*XT_P + l] = f2bf(bf2f(xv[j]) * dtl);
      U [(p4 + j)*XT_P + l] = f2bf(bf2f(bv[j]) * dec);
    }
  }
  __syncthreads();

  {
    f32x4 sacc[4] = {};
    for (int k2 = 0; k2 < 8; ++k2){
      int kc = k2*32 + (lane >> 4)*8;
      short8 a = *(const short8*)&U[(w*16 + (lane & 15))*XT_P + kc];
#pragma unroll
      for (int pt = 0; pt < 4; ++pt){
        short8 bfr = *(const short8*)&Xt[(pt*16 + (lane & 15))*XT_P + kc];
        sacc[pt] = __builtin_amdgcn_mfma_f32_16x16x32_bf16(a, bfr, sacc[pt], 0, 0, 0);
      }
    }
    float* sp = states + (((size_t)b*NCHUNK + z)*NHEADS + hh)*(DHEAD*DSTATE);
#pragma unroll
    for (int pt = 0; pt < 4; ++pt){
      int p = pt*16 + (lane & 15);
#pragma unroll
      for (int r = 0; r < 4; ++r){
        int n = w*16 + (lane >> 4)*4 + r;
        sp[p*DSTATE + n] = sacc[pt][r];
      }
    }
  }
  __syncthreads();   // all waves done reading U (Btdec)

  const unsigned short* Gp = Gb + (((size_t)b*NCHUNK + z) << 16);
  f32x4 yacc[4][4] = {};
  for (int st = 0; st < 8; ++st){
    short8 xb[4];
#pragma unroll
    for (int pt = 0; pt < 4; ++pt)
      xb[pt] = *(const short8*)&Xt[(pt*16 + (lane & 15))*XT_P + st*32 + (lane >> 4)*8];
    const int s0 = st*32 + (lane >> 4)*8;
    float es[8];
#pragma unroll
    for (int j = 0; j < 8; ++j) es[j] = sdA[s0 + j];
#pragma unroll
    for (int lt = 0; lt < 4; ++lt){
      int lg = w + lt*4;
      if (st*32 > lg*16 + 15) continue;          // s-tile fully above diagonal
      int l = lg*16 + (lane & 15);
      float el = sdA[l];
      short8 gv = *(const short8*)&Gp[(size_t)l*256 + s0];
      short8 mf;
#pragma unroll
      for (int j = 0; j < 8; ++j){
        float m = (s0 + j <= l) ? bf2f((unsigned short)gv[j]) * __expf(el - es[j]) : 0.f;
        mf[j] = (short)f2bf(m);
      }
#pragma unroll
      for (int pt = 0; pt < 4; ++pt)
        yacc[lt][pt] = __builtin_amdgcn_mfma_f32_16x16x32_bf16(mf, xb[pt], yacc[lt][pt], 0, 0, 0);
    }
  }
  __syncthreads();   // U becomes Ystage

  unsigned short* Yst = U + w * 4096;
#pragma unroll
  for (int lt = 0; lt < 4; ++lt)
#pragma unroll
    for (int pt = 0; pt < 4; ++pt)
#pragma unroll
      for (int r = 0; r < 4; ++r){
        int row = lt*16 + (lane >> 4)*4 + r;
        int c = pt*16 + (lane & 15);
        int cs = (c & 7) | ((((c >> 3) ^ (row & 7)) & 7) << 3);
        Yst[row*64 + cs] = f2bf(yacc[lt][pt][r]);
      }
  __syncthreads();
  {
    int ltl = lane >> 4, rr = lane & 15;
    int row = ltl*16 + rr;
    int lg = (w + ltl*4)*16 + rr;
    unsigned short* dst = Yb + (row0 + lg)*DINNER + hh*DHEAD;
#pragma unroll
    for (int k = 0; k < 8; ++k){
      short8 v = *(const short8*)&Yst[row*64 + ((k ^ (row & 7)) << 3)];
      *(short8*)(dst + k*8) = v;
    }
  }
}

// ---------- sequential inter-chunk recurrence; 4-way split for latency overlap ----------
__launch_bounds__(256)
__global__ void state_recur_kernel(const float* __restrict__ states, const float* __restrict__ dAcs_g,
                                   unsigned short* __restrict__ prev_bf){
  const int hh = blockIdx.x, b = blockIdx.y, q = blockIdx.z;   // q: quarter of the state
  const int t = threadIdx.x;
  float S[4];
#pragma unroll
  for (int k = 0; k < 4; ++k) S[k] = 0.f;
  for (int z = 0; z < NCHUNK; ++z){
    size_t base = (((size_t)b*NCHUNK + z)*NHEADS + hh)*(DHEAD*DSTATE) + (size_t)q*1024;
    float cd = __expf(dAcs_g[(((size_t)(b*NHEADS + hh))*NCHUNK + z)*CHUNK + CHUNK-1]);
#pragma unroll
    for (int k = 0; k < 4; ++k){
      size_t idx = base + (size_t)k*256 + t;
      float st = states[idx];
      prev_bf[idx] = f2bf(S[k]);
      S[k] = S[k]*cd + st;
    }
  }
}

// ---------- FUSED: Yo=eA*(C.prev^T) + Yd + D*X, gate with silu(z), RMSNorm -> yn ----------
__launch_bounds__(512, 2)
__global__ void chunk_fin_kernel(const unsigned short* __restrict__ X,
                                 const unsigned short* __restrict__ Cm,
                                 const unsigned short* __restrict__ zx,
                                 const float* __restrict__ dAcs_g,
                                 const unsigned short* __restrict__ prev_bf,
                                 const float* __restrict__ Dp,
                                 const unsigned short* __restrict__ Yb,
                                 const float* __restrict__ gnw,
                                 unsigned short* __restrict__ yn){
  const int s = blockIdx.x;                 // 0..255: z*16 + slice
  const int b = blockIdx.y;
  const int z = s >> 4, sl = s & 15;
  const int t = threadIdx.x, w = t >> 6, lane = t & 63;
  const size_t row0 = (size_t)b*LSEQ + z*CHUNK + sl*16;
  __shared__ __align__(16) unsigned short Yg[16][2056];   // padded: row stride 4112B
  __shared__ float seA[NHEADS][16];
  __shared__ float sDp[NHEADS];

  {
    int hh = t >> 4, r = t & 15;
    seA[hh][r] = __expf(dAcs_g[(((size_t)(b*NHEADS + hh))*NCHUNK + z)*CHUNK + sl*16 + r]);
    if (t < NHEADS) sDp[t] = Dp[t];
  }
  __syncthreads();

  short8 cf[2];
#pragma unroll
  for (int k2 = 0; k2 < 2; ++k2)
    cf[k2] = *(const short8*)(Cm + (row0 + (lane & 15))*DSTATE + k2*32 + (lane >> 4)*8);

  for (int hi = 0; hi < 4; ++hi){
    int hh = w*4 + hi;
    const unsigned short* pvb = prev_bf + (((size_t)b*NCHUNK + z)*NHEADS + hh)*(DHEAD*DSTATE);
    f32x4 acc[4] = {};
#pragma unroll
    for (int k2 = 0; k2 < 2; ++k2){
      int kc = k2*32 + (lane >> 4)*8;
#pragma unroll
      for (int pt = 0; pt < 4; ++pt){
        short8 bv = *(const short8*)(pvb + (size_t)(pt*16 + (lane & 15))*DSTATE + kc);
        acc[pt] = __builtin_amdgcn_mfma_f32_16x16x32_bf16(cf[k2], bv, acc[pt], 0, 0, 0);
      }
    }
#pragma unroll
    for (int pt = 0; pt < 4; ++pt){
      int c = hh*DHEAD + pt*16 + (lane & 15);
#pragma unroll
      for (int r = 0; r < 4; ++r){
        int row = (lane >> 4)*4 + r;
        Yg[row][c] = f2bf(acc[pt][r] * seA[hh][row]);
      }
    }
  }
  __syncthreads();

  const int row = t >> 5, i = t & 31;
  const size_t grow = row0 + row;
  float ss = 0.f;
#pragma unroll
  for (int j = 0; j < 8; ++j){
    int c0 = i*8 + j*256;
    short8 yo = *(const short8*)&Yg[row][c0];
    short8 yd = *(const short8*)(Yb + grow*DINNER + c0);
    short8 xv = *(const short8*)(X  + grow*DINNER + c0);
    short8 zv = *(const short8*)(zx + grow*DINPROJ + c0);
    float Dh = sDp[c0 >> 6];
    short8 og;
#pragma unroll
    for (int q = 0; q < 8; ++q){
      float y = bf2f((unsigned short)yd[q]) + bf2f((unsigned short)yo[q])
              + Dh*bf2f((unsigned short)xv[q]);
      float zf = bf2f((unsigned short)zv[q]);
      float g = y * (zf / (1.f + __expf(-zf)));
      ss += g*g;
      og[q] = (short)f2bf(g);
    }
    *(short8*)&Yg[row][c0] = og;
  }
  for (int off = 16; off; off >>= 1) ss += __shfl_down(ss, off, 32);
  float sc = __shfl(ss, 0, 32);
  sc = rsqrtf(sc * (1.f/DINNER) + 1e-5f);
  __syncthreads();

#pragma unroll
  for (int j = 0; j < 8; ++j){
    int c0 = i*8 + j*256;
    short8 g = *(const short8*)&Yg[row][c0];
    f32x4 w0 = *(const f32x4*)(gnw + c0);
    f32x4 w1 = *(const f32x4*)(gnw + c0 + 4);
    short8 o;
#pragma unroll
    for (int q = 0; q < 4; ++q) o[q]   = (short)f2bf(bf2f((unsigned short)g[q])  *sc*w0[q]);
#pragma unroll
    for (int q = 0; q < 4; ++q) o[q+4] = (short)f2bf(bf2f((unsigned short)g[q+4])*sc*w1[q]);
    *(short8*)(yn + grow*DINNER + c0) = o;
  }
}

// ---------- launch ----------
extern "C" void kernel_launch(void* const* d_in, const int* in_sizes, int n_in,
                              void* d_out, int out_size, void* d_ws, size_t ws_size,
                              hipStream_t stream){
  const float* x      = (const float*)d_in[0];
  const float* in_w   = (const float*)d_in[1];
  const float* conv_w = (const float*)d_in[2];
  const float* conv_b = (const float*)d_in[3];
  const float* dt_b   = (const float*)d_in[4];
  const float* A_log  = (const float*)d_in[5];
  const float* Dp     = (const float*)d_in[6];
  const float* gnw    = (const float*)d_in[7];
  const float* out_w  = (const float*)d_in[8];
  const float* norm_w = (const float*)d_in[9];
  float* outp = (float*)d_out;

  const size_t NEEDED =
      (size_t)NROWS*DMODEL*2
    + (size_t)2*NPAD*DMODEL*2 + (size_t)2*DMODEL*DINNER*2       // wA[2], wO[2]
    + (size_t)NROWS*DINPROJ*2 + (size_t)NROWS*DINNER*2 /*X*/ + (size_t)NROWS*DINNER*2 /*Yb*/
    + (size_t)NROWS*DSTATE*2*2 + (size_t)BSZ*NHEADS*LSEQ*4
    + (size_t)BSZ*NHEADS*NCHUNK*CHUNK*4
    + (size_t)BSZ*NCHUNK*NHEADS*DHEAD*DSTATE*4
    + (size_t)BSZ*NCHUNK*NHEADS*DHEAD*DSTATE*2   /* prev_bf */
    + (size_t)BSZ*NCHUNK*CHUNK*CHUNK*2           /* Gb */
    + 48*256;
  if (ws_size < NEEDED) return;   // clean fail signals ws too small

  char* p = (char*)d_ws;
  auto alloc = [&](size_t n){ char* r = p; p += (n + 255) & ~(size_t)255; return (void*)r; };
  unsigned short* h    = (unsigned short*)alloc((size_t)NROWS*DMODEL*2);
  unsigned short* wA   = (unsigned short*)alloc((size_t)2*NPAD*DMODEL*2);
  unsigned short* wO   = (unsigned short*)alloc((size_t)2*DMODEL*DINNER*2);
  unsigned short* zx   = (unsigned short*)alloc((size_t)NROWS*DINPROJ*2);
  unsigned short* X    = (unsigned short*)alloc((size_t)NROWS*DINNER*2);
  unsigned short* Yb   = (unsigned short*)alloc((size_t)NROWS*DINNER*2);
  unsigned short* Bm   = (unsigned short*)alloc((size_t)NROWS*DSTATE*2);
  unsigned short* Cm   = (unsigned short*)alloc((size_t)NROWS*DSTATE*2);
  float* dtbuf  = (float*)alloc((size_t)BSZ*NHEADS*LSEQ*4);
  float* dAcs   = (float*)alloc((size_t)BSZ*NHEADS*NCHUNK*CHUNK*4);
  float* states = (float*)alloc((size_t)BSZ*NCHUNK*NHEADS*DHEAD*DSTATE*4);
  unsigned short* prev_bf = (unsigned short*)alloc((size_t)BSZ*NCHUNK*NHEADS*DHEAD*DSTATE*2);
  unsigned short* Gb = (unsigned short*)alloc((size_t)BSZ*NCHUNK*CHUNK*CHUNK*2);
  unsigned short* yn = X;   // alias: all X reads in chunk_fin precede yn writes (same rows)

  { // cast both layers' weights once
    long long total = (long long)2*NPAD*DMODEL + (long long)2*DMODEL*DINNER;
    cast_all_kernel<<<(int)((total + 255)/256), 256, 0, stream>>>(in_w, out_w, wA, wO);
  }

  for (int layer = 0; layer < 2; ++layer){
    const float* xprev = (layer == 0) ? x : outp;
    float* xnext = outp;
    const unsigned short* wAl = wA + (size_t)layer*NPAD*DMODEL;
    const unsigned short* wOl = wO + (size_t)layer*DMODEL*DINNER;

    rmsnorm_kernel<<<NROWS/4, 256, 0, stream>>>(xprev, norm_w + layer*DMODEL, h);
    gemm_bt<0><<<dim3(NPAD/128, NROWS/128), 256, 0, stream>>>(
        h, wAl, (void*)zx, nullptr, DMODEL, DINPROJ);
    conv_silu_kernel<<<((CONVDIM/8)*(NROWS/64) + 255)/256, 256, 0, stream>>>(
        zx, conv_w + (size_t)layer*CONVDIM*4, conv_b + layer*CONVDIM, X, Bm, Cm);
    dtscan_kernel<<<dim3(NCHUNK, NHEADS, BSZ), 256, 0, stream>>>(
        zx, dt_b + layer*NHEADS, A_log + layer*NHEADS, dtbuf, dAcs);
    gram_kernel<<<dim3(NCHUNK*4, BSZ), 256, 0, stream>>>(Bm, Cm, Gb);
    chunk_main_kernel<<<dim3(NCHUNK, NHEADS, BSZ), 256, 0, stream>>>(
        X, Bm, Gb, dtbuf, dAcs, states, Yb);
    state_recur_kernel<<<dim3(NHEADS, BSZ, 4), 256, 0, stream>>>(states, dAcs, prev_bf);
    chunk_fin_kernel<<<dim3(256, BSZ), 512, 0, stream>>>(
        X, Cm, zx, dAcs, prev_bf, Dp + layer*NHEADS, Yb, gnw + (size_t)layer*DINNER, yn);
    gemm_bt<1><<<dim3(DMODEL/128, NROWS/128), 256, 0, stream>>>(
        yn, wOl, (void*)xnext, xprev, DINNER, DMODEL);
  }
  (void)in_sizes; (void)n_in; (void)out_size;
}

// Round 16
// 673.862 us; speedup vs baseline: 1.0615x; 1.0058x over previous
//
#include <hip/hip_runtime.h>

// ---------- constants ----------
#define DMODEL   1024
#define DINNER   2048
#define NHEADS   32
#define DHEAD    64
#define DSTATE   64
#define CONVDIM  2176
#define DINPROJ  4256
#define LSEQ     4096
#define BSZ      2
#define NCHUNK   16
#define CHUNK    256
#define NROWS    8192      // BSZ*LSEQ
#define NPAD     4352      // 34*128, padded in_proj rows
#define XT_P     264       // LDS transpose pitch (mult of 8, 2-way banks)

typedef __attribute__((ext_vector_type(8))) short  short8;
typedef __attribute__((ext_vector_type(4))) float  f32x4;
typedef __attribute__((ext_vector_type(4))) unsigned short us4;

__device__ __forceinline__ float bf2f(unsigned short u){
  return __uint_as_float(((unsigned int)u) << 16);
}
__device__ __forceinline__ unsigned short f2bf(float f){
  unsigned int i = __float_as_uint(f);
  i += 0x7fffu + ((i >> 16) & 1u);     // round-to-nearest-even
  return (unsigned short)(i >> 16);
}

// async global->LDS, 16B per lane (dest = wave-uniform base + lane*16)
__device__ __forceinline__ void gl_lds16(const void* g, void* l){
  __builtin_amdgcn_global_load_lds(
      (const __attribute__((address_space(1))) unsigned int*)g,
      (__attribute__((address_space(3))) unsigned int*)l, 16, 0, 0);
}

// ---------- cast ALL weights (both layers) -> bf16 once ----------
__global__ void cast_all_kernel(const float* __restrict__ in_w, const float* __restrict__ out_w,
                                unsigned short* __restrict__ wA, unsigned short* __restrict__ wO){
  const long long nA = (long long)2*NPAD*DMODEL;
  const long long nO = (long long)2*DMODEL*DINNER;
  long long i = (long long)blockIdx.x*256 + threadIdx.x;
  if (i < nA){
    long long layer = i / ((long long)NPAD*DMODEL);
    long long j = i - layer*((long long)NPAD*DMODEL);
    long long r = j / DMODEL;
    wA[i] = (r < DINPROJ)
        ? f2bf(in_w[layer*((long long)DINPROJ*DMODEL) + r*DMODEL + (j - r*DMODEL)])
        : (unsigned short)0;
  } else if (i < nA + nO){
    long long k = i - nA;
    wO[k] = f2bf(out_w[k]);
  }
}

// ---------- RMSNorm: wave-per-row, shuffle-only (f32 in -> bf16 out) ----------
__launch_bounds__(256)
__global__ void rmsnorm_kernel(const float* __restrict__ x, const float* __restrict__ w,
                               unsigned short* __restrict__ out){
  const int r = blockIdx.x*4 + (threadIdx.x >> 6);
  const int lane = threadIdx.x & 63;
  const float* xr = x + (size_t)r*DMODEL;
  f32x4 v[4]; float s = 0.f;
#pragma unroll
  for (int i = 0; i < 4; ++i){
    v[i] = *(const f32x4*)(xr + lane*4 + i*256);
#pragma unroll
    for (int j = 0; j < 4; ++j) s += v[i][j]*v[i][j];
  }
  for (int off = 32; off; off >>= 1) s += __shfl_down(s, off, 64);
  s = __shfl(s, 0, 64);
  const float sc = rsqrtf(s*(1.f/DMODEL) + 1e-5f);
#pragma unroll
  for (int i = 0; i < 4; ++i){
    us4 o;
    const float* wp = w + lane*4 + i*256;
#pragma unroll
    for (int j = 0; j < 4; ++j) o[j] = f2bf(v[i][j]*sc*wp[j]);
    *(us4*)(out + (size_t)r*DMODEL + lane*4 + i*256) = o;
  }
}

// ---------- bf16 MFMA GEMM, C[i,j] = sum_k A[i,k]*B[j,k]  (m97 structure, proven) ----------
template<int EPI>
__launch_bounds__(256, 3)
__global__ void gemm_bt(const unsigned short* __restrict__ A, const unsigned short* __restrict__ Bw,
                        void* __restrict__ Cout, const float* __restrict__ Cres,
                        int K, int Nstore){
  __shared__ __align__(16) unsigned short As[128*64];
  __shared__ __align__(16) unsigned short Bs[128*64];
  const int m0 = blockIdx.y * 128, n0 = blockIdx.x * 128;
  const int t = threadIdx.x, w = t >> 6, lane = t & 63;
  const int wr = w >> 1, wc = w & 1;
  const int srow = lane >> 3;           // 0..7
  const int scol = (lane & 7) * 8;      // 0..56
  f32x4 acc[4][4] = {};

  for (int k0 = 0; k0 < K; k0 += 64){
#pragma unroll
    for (int it = 0; it < 4; ++it){
      int rr = (w*4 + it)*8 + srow;
      gl_lds16(A  + (size_t)(m0 + rr)*K + k0 + scol, &As[(w*4 + it)*512]);
      gl_lds16(Bw + (size_t)(n0 + rr)*K + k0 + scol, &Bs[(w*4 + it)*512]);
    }
    __syncthreads();
#pragma unroll
    for (int kk = 0; kk < 64; kk += 32){
      short8 af[4], bfr[4];
      int col = kk + (lane >> 4)*8;
#pragma unroll
      for (int m = 0; m < 4; ++m)
        af[m] = *(const short8*)&As[(wr*64 + m*16 + (lane & 15))*64 + col];
#pragma unroll
      for (int n = 0; n < 4; ++n)
        bfr[n] = *(const short8*)&Bs[(wc*64 + n*16 + (lane & 15))*64 + col];
#pragma unroll
      for (int m = 0; m < 4; ++m)
#pragma unroll
        for (int n = 0; n < 4; ++n)
          acc[m][n] = __builtin_amdgcn_mfma_f32_16x16x32_bf16(af[m], bfr[n], acc[m][n], 0, 0, 0);
    }
    __syncthreads();
  }

#pragma unroll
  for (int m = 0; m < 4; ++m){
#pragma unroll
    for (int n = 0; n < 4; ++n){
      int col = n0 + wc*64 + n*16 + (lane & 15);
      if (col < Nstore){
#pragma unroll
        for (int r = 0; r < 4; ++r){
          int row = m0 + wr*64 + m*16 + (lane >> 4)*4 + r;
          if (EPI == 0)
            ((unsigned short*)Cout)[(size_t)row*Nstore + col] = f2bf(acc[m][n][r]);
          else
            ((float*)Cout)[(size_t)row*Nstore + col] =
                Cres[(size_t)row*Nstore + col] + acc[m][n][r];
        }
      }
    }
  }
}

// ---------- causal conv1d (K=4) + silu, 8 channels/thread, rolling taps ----------
__global__ void conv_silu_kernel(const unsigned short* __restrict__ zx,
                                 const float* __restrict__ cw, const float* __restrict__ cb,
                                 unsigned short* __restrict__ X, unsigned short* __restrict__ Bm,
                                 unsigned short* __restrict__ Cm){
  int gid = blockIdx.x*256 + threadIdx.x;
  if (gid >= (CONVDIM/8)*(NROWS/64)) return;
  const int oc = gid % (CONVDIM/8);
  const int rb = gid / (CONVDIM/8);
  const int c = oc*8;
  const size_t r0 = (size_t)rb*64;
  const int l0 = (int)(r0 & (LSEQ-1));
  float w[4][8], bias[8];
#pragma unroll
  for (int j = 0; j < 8; ++j){
    bias[j] = cb[c+j];
#pragma unroll
    for (int i = 0; i < 4; ++i) w[i][j] = cw[(c+j)*4 + i];
  }
  const unsigned short* src = zx + DINNER + c;
  float p[3][8];
#pragma unroll
  for (int i = 0; i < 3; ++i){
    if (l0 - 3 + i >= 0){
      short8 v = *(const short8*)(src + (r0 - 3 + i)*DINPROJ);
#pragma unroll
      for (int j = 0; j < 8; ++j) p[i][j] = bf2f((unsigned short)v[j]);
    } else {
#pragma unroll
      for (int j = 0; j < 8; ++j) p[i][j] = 0.f;
    }
  }
  for (int it = 0; it < 64; ++it){
    const size_t r = r0 + it;
    short8 v = *(const short8*)(src + r*DINPROJ);
    float cur[8];
    short8 ov;
#pragma unroll
    for (int j = 0; j < 8; ++j){
      cur[j] = bf2f((unsigned short)v[j]);
      float a = bias[j] + w[0][j]*p[0][j] + w[1][j]*p[1][j] + w[2][j]*p[2][j] + w[3][j]*cur[j];
      float s = a / (1.f + __expf(-a));
      ov[j] = (short)f2bf(s);
    }
    if (c < DINNER)             *(short8*)(X  + r*DINNER + c) = ov;
    else if (c < DINNER+DSTATE) *(short8*)(Bm + r*DSTATE + (c-DINNER)) = ov;
    else                        *(short8*)(Cm + r*DSTATE + (c-DINNER-DSTATE)) = ov;
#pragma unroll
    for (int j = 0; j < 8; ++j){ p[0][j]=p[1][j]; p[1][j]=p[2][j]; p[2][j]=cur[j]; }
  }
}

// ---------- G = C . B^T per (b,z): head-independent Gram matrix, bf16 ----------
__launch_bounds__(256, 4)
__global__ void gram_kernel(const unsigned short* __restrict__ Bm,
                            const unsigned short* __restrict__ Cm,
                            unsigned short* __restrict__ Gb){
  const int zq = blockIdx.x, b = blockIdx.y;
  const int z = zq >> 2, rq = zq & 3;
  const int t = threadIdx.x, w = t >> 6, lane = t & 63;
  const size_t row0 = (size_t)b*LSEQ + z*CHUNK;
  f32x4 acc[4][4] = {};
#pragma unroll
  for (int k2 = 0; k2 < 2; ++k2){
    int kc = k2*32 + (lane >> 4)*8;
    short8 cf[4], bfr[4];
#pragma unroll
    for (int mf = 0; mf < 4; ++mf)
      cf[mf] = *(const short8*)(Cm + (row0 + rq*64 + mf*16 + (lane & 15))*DSTATE + kc);
#pragma unroll
    for (int nf = 0; nf < 4; ++nf)
      bfr[nf] = *(const short8*)(Bm + (row0 + w*64 + nf*16 + (lane & 15))*DSTATE + kc);
#pragma unroll
    for (int mf = 0; mf < 4; ++mf)
#pragma unroll
      for (int nf = 0; nf < 4; ++nf)
        acc[mf][nf] = __builtin_amdgcn_mfma_f32_16x16x32_bf16(cf[mf], bfr[nf], acc[mf][nf], 0, 0, 0);
  }
  unsigned short* Gp = Gb + (((size_t)b*NCHUNK + z) << 16);
#pragma unroll
  for (int mf = 0; mf < 4; ++mf)
#pragma unroll
    for (int nf = 0; nf < 4; ++nf)
#pragma unroll
      for (int r = 0; r < 4; ++r){
        int row = rq*64 + mf*16 + (lane >> 4)*4 + r;
        int col = w*64 + nf*16 + (lane & 15);
        Gp[(size_t)row*256 + col] = f2bf(acc[mf][nf][r]);
      }
}

// ---------- per-(b,chunk,head): inline dt-scan + states + Yd (G precomputed) ----------
__launch_bounds__(256, 2)
__global__ void chunk_main_kernel(const unsigned short* __restrict__ X,
                                  const unsigned short* __restrict__ Bm,
                                  const unsigned short* __restrict__ Gb,
                                  const unsigned short* __restrict__ zx,
                                  const float* __restrict__ dtb,
                                  const float* __restrict__ A_log,
                                  float* __restrict__ dAcs_g,
                                  float* __restrict__ states,
                                  unsigned short* __restrict__ Yb){
  const int z = blockIdx.x, hh = blockIdx.y, b = blockIdx.z;
  const int t = threadIdx.x, w = t >> 6, lane = t & 63;
  __shared__ __align__(16) unsigned short Xt[64 * XT_P];   // Xdt^T [p][l]
  __shared__ __align__(16) unsigned short U[64 * XT_P];    // union: Btdec -> Ystage
  __shared__ float sdA[CHUNK];
  __shared__ float sdt[CHUNK];
  __shared__ float wsum[4];

  const size_t row0 = (size_t)b*LSEQ + z*CHUNK;
  const size_t hb = (size_t)(b*NHEADS + hh);

  // ---- inline dt softplus + inclusive scan of dA (replaces dtscan kernel) ----
  {
    const float Ah = -__expf(A_log[hh]);
    float raw = bf2f(zx[(row0 + t)*DINPROJ + DINNER + CONVDIM + hh]) + dtb[hh];
    float dtv = raw > 20.f ? raw : log1pf(__expf(raw));
    float v = dtv * Ah;
#pragma unroll
    for (int off = 1; off < 64; off <<= 1){
      float u = __shfl_up(v, off, 64);
      if (lane >= off) v += u;
    }
    if (lane == 63) wsum[w] = v;
    __syncthreads();
    float pre = 0.f;
#pragma unroll
    for (int j = 0; j < 3; ++j) if (j < w) pre += wsum[j];
    v += pre;
    sdt[t] = dtv;
    sdA[t] = v;
    dAcs_g[(hb*NCHUNK + z)*CHUNK + t] = v;   // for state_recur + chunk_fin
    __syncthreads();
  }
  const float total = sdA[CHUNK-1];

  for (int it = 0; it < 16; ++it){
    int l = it*16 + (t >> 4);
    int p4 = (t & 15) * 4;
    float dtl = sdt[l];
    float dec = __expf(total - sdA[l]);
    us4 xv = *(const us4*)(X  + (row0 + l)*DINNER + hh*DHEAD + p4);
    us4 bv = *(const us4*)(Bm + (row0 + l)*DSTATE + p4);
#pragma unroll
    for (int j = 0; j < 4; ++j){
      Xt[(p4 + j)*XT_P + l] = f2bf(bf2f(xv[j]) * dtl);
      U [(p4 + j)*XT_P + l] = f2bf(bf2f(bv[j]) * dec);
    }
  }
  __syncthreads();

  {
    f32x4 sacc[4] = {};
    for (int k2 = 0; k2 < 8; ++k2){
      int kc = k2*32 + (lane >> 4)*8;
      short8 a = *(const short8*)&U[(w*16 + (lane & 15))*XT_P + kc];
#pragma unroll
      for (int pt = 0; pt < 4; ++pt){
        short8 bfr = *(const short8*)&Xt[(pt*16 + (lane & 15))*XT_P + kc];
        sacc[pt] = __builtin_amdgcn_mfma_f32_16x16x32_bf16(a, bfr, sacc[pt], 0, 0, 0);
      }
    }
    float* sp = states + (((size_t)b*NCHUNK + z)*NHEADS + hh)*(DHEAD*DSTATE);
#pragma unroll
    for (int pt = 0; pt < 4; ++pt){
      int p = pt*16 + (lane & 15);
#pragma unroll
      for (int r = 0; r < 4; ++r){
        int n = w*16 + (lane >> 4)*4 + r;
        sp[p*DSTATE + n] = sacc[pt][r];
      }
    }
  }
  __syncthreads();   // all waves done reading U (Btdec)

  const unsigned short* Gp = Gb + (((size_t)b*NCHUNK + z) << 16);
  f32x4 yacc[4][4] = {};
  for (int st = 0; st < 8; ++st){
    short8 xb[4];
#pragma unroll
    for (int pt = 0; pt < 4; ++pt)
      xb[pt] = *(const short8*)&Xt[(pt*16 + (lane & 15))*XT_P + st*32 + (lane >> 4)*8];
    const int s0 = st*32 + (lane >> 4)*8;
    float es[8];
#pragma unroll
    for (int j = 0; j < 8; ++j) es[j] = sdA[s0 + j];
#pragma unroll
    for (int lt = 0; lt < 4; ++lt){
      int lg = w + lt*4;
      if (st*32 > lg*16 + 15) continue;          // s-tile fully above diagonal
      int l = lg*16 + (lane & 15);
      float el = sdA[l];
      short8 gv = *(const short8*)&Gp[(size_t)l*256 + s0];
      short8 mf;
#pragma unroll
      for (int j = 0; j < 8; ++j){
        float m = (s0 + j <= l) ? bf2f((unsigned short)gv[j]) * __expf(el - es[j]) : 0.f;
        mf[j] = (short)f2bf(m);
      }
#pragma unroll
      for (int pt = 0; pt < 4; ++pt)
        yacc[lt][pt] = __builtin_amdgcn_mfma_f32_16x16x32_bf16(mf, xb[pt], yacc[lt][pt], 0, 0, 0);
    }
  }
  __syncthreads();   // U becomes Ystage

  unsigned short* Yst = U + w * 4096;
#pragma unroll
  for (int lt = 0; lt < 4; ++lt)
#pragma unroll
    for (int pt = 0; pt < 4; ++pt)
#pragma unroll
      for (int r = 0; r < 4; ++r){
        int row = lt*16 + (lane >> 4)*4 + r;
        int c = pt*16 + (lane & 15);
        int cs = (c & 7) | ((((c >> 3) ^ (row & 7)) & 7) << 3);
        Yst[row*64 + cs] = f2bf(yacc[lt][pt][r]);
      }
  __syncthreads();
  {
    int ltl = lane >> 4, rr = lane & 15;
    int row = ltl*16 + rr;
    int lg = (w + ltl*4)*16 + rr;
    unsigned short* dst = Yb + (row0 + lg)*DINNER + hh*DHEAD;
#pragma unroll
    for (int k = 0; k < 8; ++k){
      short8 v = *(const short8*)&Yst[row*64 + ((k ^ (row & 7)) << 3)];
      *(short8*)(dst + k*8) = v;
    }
  }
}

// ---------- sequential inter-chunk recurrence; 4-way split for latency overlap ----------
__launch_bounds__(256)
__global__ void state_recur_kernel(const float* __restrict__ states, const float* __restrict__ dAcs_g,
                                   unsigned short* __restrict__ prev_bf){
  const int hh = blockIdx.x, b = blockIdx.y, q = blockIdx.z;   // q: quarter of the state
  const int t = threadIdx.x;
  float S[4];
#pragma unroll
  for (int k = 0; k < 4; ++k) S[k] = 0.f;
  for (int z = 0; z < NCHUNK; ++z){
    size_t base = (((size_t)b*NCHUNK + z)*NHEADS + hh)*(DHEAD*DSTATE) + (size_t)q*1024;
    float cd = __expf(dAcs_g[(((size_t)(b*NHEADS + hh))*NCHUNK + z)*CHUNK + CHUNK-1]);
#pragma unroll
    for (int k = 0; k < 4; ++k){
      size_t idx = base + (size_t)k*256 + t;
      float st = states[idx];
      prev_bf[idx] = f2bf(S[k]);
      S[k] = S[k]*cd + st;
    }
  }
}

// ---------- FUSED: Yo=eA*(C.prev^T) + Yd + D*X, gate with silu(z), RMSNorm -> yn ----------
__launch_bounds__(512, 2)
__global__ void chunk_fin_kernel(const unsigned short* __restrict__ X,
                                 const unsigned short* __restrict__ Cm,
                                 const unsigned short* __restrict__ zx,
                                 const float* __restrict__ dAcs_g,
                                 const unsigned short* __restrict__ prev_bf,
                                 const float* __restrict__ Dp,
                                 const unsigned short* __restrict__ Yb,
                                 const float* __restrict__ gnw,
                                 unsigned short* __restrict__ yn){
  const int s = blockIdx.x;                 // 0..255: z*16 + slice
  const int b = blockIdx.y;
  const int z = s >> 4, sl = s & 15;
  const int t = threadIdx.x, w = t >> 6, lane = t & 63;
  const size_t row0 = (size_t)b*LSEQ + z*CHUNK + sl*16;
  __shared__ __align__(16) unsigned short Yg[16][2056];   // padded: row stride 4112B
  __shared__ float seA[NHEADS][16];
  __shared__ float sDp[NHEADS];

  {
    int hh = t >> 4, r = t & 15;
    seA[hh][r] = __expf(dAcs_g[(((size_t)(b*NHEADS + hh))*NCHUNK + z)*CHUNK + sl*16 + r]);
    if (t < NHEADS) sDp[t] = Dp[t];
  }
  __syncthreads();

  short8 cf[2];
#pragma unroll
  for (int k2 = 0; k2 < 2; ++k2)
    cf[k2] = *(const short8*)(Cm + (row0 + (lane & 15))*DSTATE + k2*32 + (lane >> 4)*8);

  for (int hi = 0; hi < 4; ++hi){
    int hh = w*4 + hi;
    const unsigned short* pvb = prev_bf + (((size_t)b*NCHUNK + z)*NHEADS + hh)*(DHEAD*DSTATE);
    f32x4 acc[4] = {};
#pragma unroll
    for (int k2 = 0; k2 < 2; ++k2){
      int kc = k2*32 + (lane >> 4)*8;
#pragma unroll
      for (int pt = 0; pt < 4; ++pt){
        short8 bv = *(const short8*)(pvb + (size_t)(pt*16 + (lane & 15))*DSTATE + kc);
        acc[pt] = __builtin_amdgcn_mfma_f32_16x16x32_bf16(cf[k2], bv, acc[pt], 0, 0, 0);
      }
    }
#pragma unroll
    for (int pt = 0; pt < 4; ++pt){
      int c = hh*DHEAD + pt*16 + (lane & 15);
#pragma unroll
      for (int r = 0; r < 4; ++r){
        int row = (lane >> 4)*4 + r;
        Yg[row][c] = f2bf(acc[pt][r] * seA[hh][row]);
      }
    }
  }
  __syncthreads();

  const int row = t >> 5, i = t & 31;
  const size_t grow = row0 + row;
  float ss = 0.f;
#pragma unroll
  for (int j = 0; j < 8; ++j){
    int c0 = i*8 + j*256;
    short8 yo = *(const short8*)&Yg[row][c0];
    short8 yd = *(const short8*)(Yb + grow*DINNER + c0);
    short8 xv = *(const short8*)(X  + grow*DINNER + c0);
    short8 zv = *(const short8*)(zx + grow*DINPROJ + c0);
    float Dh = sDp[c0 >> 6];
    short8 og;
#pragma unroll
    for (int q = 0; q < 8; ++q){
      float y = bf2f((unsigned short)yd[q]) + bf2f((unsigned short)yo[q])
              + Dh*bf2f((unsigned short)xv[q]);
      float zf = bf2f((unsigned short)zv[q]);
      float g = y * (zf / (1.f + __expf(-zf)));
      ss += g*g;
      og[q] = (short)f2bf(g);
    }
    *(short8*)&Yg[row][c0] = og;
  }
  for (int off = 16; off; off >>= 1) ss += __shfl_down(ss, off, 32);
  float sc = __shfl(ss, 0, 32);
  sc = rsqrtf(sc * (1.f/DINNER) + 1e-5f);
  __syncthreads();

#pragma unroll
  for (int j = 0; j < 8; ++j){
    int c0 = i*8 + j*256;
    short8 g = *(const short8*)&Yg[row][c0];
    f32x4 w0 = *(const f32x4*)(gnw + c0);
    f32x4 w1 = *(const f32x4*)(gnw + c0 + 4);
    short8 o;
#pragma unroll
    for (int q = 0; q < 4; ++q) o[q]   = (short)f2bf(bf2f((unsigned short)g[q])  *sc*w0[q]);
#pragma unroll
    for (int q = 0; q < 4; ++q) o[q+4] = (short)f2bf(bf2f((unsigned short)g[q+4])*sc*w1[q]);
    *(short8*)(yn + grow*DINNER + c0) = o;
  }
}

// ---------- launch ----------
extern "C" void kernel_launch(void* const* d_in, const int* in_sizes, int n_in,
                              void* d_out, int out_size, void* d_ws, size_t ws_size,
                              hipStream_t stream){
  const float* x      = (const float*)d_in[0];
  const float* in_w   = (const float*)d_in[1];
  const float* conv_w = (const float*)d_in[2];
  const float* conv_b = (const float*)d_in[3];
  const float* dt_b   = (const float*)d_in[4];
  const float* A_log  = (const float*)d_in[5];
  const float* Dp     = (const float*)d_in[6];
  const float* gnw    = (const float*)d_in[7];
  const float* out_w  = (const float*)d_in[8];
  const float* norm_w = (const float*)d_in[9];
  float* outp = (float*)d_out;

  const size_t NEEDED =
      (size_t)NROWS*DMODEL*2
    + (size_t)2*NPAD*DMODEL*2 + (size_t)2*DMODEL*DINNER*2       // wA[2], wO[2]
    + (size_t)NROWS*DINPROJ*2 + (size_t)NROWS*DINNER*2 /*X*/ + (size_t)NROWS*DINNER*2 /*Yb*/
    + (size_t)NROWS*DSTATE*2*2
    + (size_t)BSZ*NHEADS*NCHUNK*CHUNK*4
    + (size_t)BSZ*NCHUNK*NHEADS*DHEAD*DSTATE*4
    + (size_t)BSZ*NCHUNK*NHEADS*DHEAD*DSTATE*2   /* prev_bf */
    + (size_t)BSZ*NCHUNK*CHUNK*CHUNK*2           /* Gb */
    + 48*256;
  if (ws_size < NEEDED) return;   // clean fail signals ws too small

  char* p = (char*)d_ws;
  auto alloc = [&](size_t n){ char* r = p; p += (n + 255) & ~(size_t)255; return (void*)r; };
  unsigned short* h    = (unsigned short*)alloc((size_t)NROWS*DMODEL*2);
  unsigned short* wA   = (unsigned short*)alloc((size_t)2*NPAD*DMODEL*2);
  unsigned short* wO   = (unsigned short*)alloc((size_t)2*DMODEL*DINNER*2);
  unsigned short* zx   = (unsigned short*)alloc((size_t)NROWS*DINPROJ*2);
  unsigned short* X    = (unsigned short*)alloc((size_t)NROWS*DINNER*2);
  unsigned short* Yb   = (unsigned short*)alloc((size_t)NROWS*DINNER*2);
  unsigned short* Bm   = (unsigned short*)alloc((size_t)NROWS*DSTATE*2);
  unsigned short* Cm   = (unsigned short*)alloc((size_t)NROWS*DSTATE*2);
  float* dAcs   = (float*)alloc((size_t)BSZ*NHEADS*NCHUNK*CHUNK*4);
  float* states = (float*)alloc((size_t)BSZ*NCHUNK*NHEADS*DHEAD*DSTATE*4);
  unsigned short* prev_bf = (unsigned short*)alloc((size_t)BSZ*NCHUNK*NHEADS*DHEAD*DSTATE*2);
  unsigned short* Gb = (unsigned short*)alloc((size_t)BSZ*NCHUNK*CHUNK*CHUNK*2);
  unsigned short* yn = X;   // alias: all X reads in chunk_fin precede yn writes (same rows)

  { // cast both layers' weights once
    long long total = (long long)2*NPAD*DMODEL + (long long)2*DMODEL*DINNER;
    cast_all_kernel<<<(int)((total + 255)/256), 256, 0, stream>>>(in_w, out_w, wA, wO);
  }

  for (int layer = 0; layer < 2; ++layer){
    const float* xprev = (layer == 0) ? x : outp;
    float* xnext = outp;
    const unsigned short* wAl = wA + (size_t)layer*NPAD*DMODEL;
    const unsigned short* wOl = wO + (size_t)layer*DMODEL*DINNER;

    rmsnorm_kernel<<<NROWS/4, 256, 0, stream>>>(xprev, norm_w + layer*DMODEL, h);
    gemm_bt<0><<<dim3(NPAD/128, NROWS/128), 256, 0, stream>>>(
        h, wAl, (void*)zx, nullptr, DMODEL, DINPROJ);
    conv_silu_kernel<<<((CONVDIM/8)*(NROWS/64) + 255)/256, 256, 0, stream>>>(
        zx, conv_w + (size_t)layer*CONVDIM*4, conv_b + layer*CONVDIM, X, Bm, Cm);
    gram_kernel<<<dim3(NCHUNK*4, BSZ), 256, 0, stream>>>(Bm, Cm, Gb);
    chunk_main_kernel<<<dim3(NCHUNK, NHEADS, BSZ), 256, 0, stream>>>(
        X, Bm, Gb, zx, dt_b + layer*NHEADS, A_log + layer*NHEADS, dAcs, states, Yb);
    state_recur_kernel<<<dim3(NHEADS, BSZ, 4), 256, 0, stream>>>(states, dAcs, prev_bf);
    chunk_fin_kernel<<<dim3(256, BSZ), 512, 0, stream>>>(
        X, Cm, zx, dAcs, prev_bf, Dp + layer*NHEADS, Yb, gnw + (size_t)layer*DINNER, yn);
    gemm_bt<1><<<dim3(DMODEL/128, NROWS/128), 256, 0, stream>>>(
        yn, wOl, (void*)xnext, xprev, DINNER, DMODEL);
  }
  (void)in_sizes; (void)n_in; (void)out_size;
}